// Round 9
// baseline (1326.207 us; speedup 1.0000x reference)
//
#include <hip/hip_runtime.h>
#include <hip/hip_bf16.h>

typedef __hip_bfloat16 bf16;
typedef unsigned short u16;
typedef __attribute__((ext_vector_type(8))) short s16x8;
typedef __attribute__((ext_vector_type(4))) short s16x4;
typedef __attribute__((ext_vector_type(4))) float f32x4;

#define EXP 3
#define BB  4
#define LL  1024
#define DD  768
#define DSN 64
#define DIN 1536
#define DTR 48
#define MM  4096       // B*L rows per expert
#define NCH 18432      // EXP*BB*DIN channels
#define NC  4          // L-chunks
#define CL  256        // steps per chunk

struct alignas(8)  bf16x4 { bf16 v[4]; };
struct alignas(16) bf16x8 { bf16 v[8]; };

__device__ __forceinline__ float siluf(float x) { return x / (1.f + __expf(-x)); }
__device__ __forceinline__ float softplusf(float x) { return (x > 15.f) ? x : log1pf(__expf(x)); }
__device__ __forceinline__ float bf2f(u16 h) { union { unsigned u; float f; } x; x.u = ((unsigned)h) << 16; return x.f; }

// DPP add: x + perm(x). quad_perm(1,0,3,2)=0xB1, quad_perm(2,3,0,1)=0x4E ->
// 4-lane allreduce in two steps (quad groups never cross channel boundaries).
template <int CTRL>
__device__ __forceinline__ float dpp_add(float x) {
  int y = __builtin_amdgcn_update_dpp(0, __float_as_int(x), CTRL, 0xf, 0xf, true);
  return x + __int_as_float(y);
}

// ---------------- LayerNorm apply + bf16 convert: per_ch -> Abf ----------------
__launch_bounds__(256)
__global__ void ln_apply_k(const float* __restrict__ pc, const float* __restrict__ lng,
                           const float* __restrict__ lnb, bf16* __restrict__ out) {
  int row  = blockIdx.x * 4 + (threadIdx.x >> 6);
  int lane = threadIdx.x & 63;
  const float* x = pc + (size_t)row * DD;
  float4 v[3];
  float s = 0.f, sq = 0.f;
#pragma unroll
  for (int i = 0; i < 3; i++) {
    v[i] = *(const float4*)(x + lane * 4 + i * 256);
    s  += v[i].x + v[i].y + v[i].z + v[i].w;
    sq += v[i].x * v[i].x + v[i].y * v[i].y + v[i].z * v[i].z + v[i].w * v[i].w;
  }
#pragma unroll
  for (int o = 1; o < 64; o <<= 1) { s += __shfl_xor(s, o); sq += __shfl_xor(sq, o); }
  float mu = s * (1.f / 768.f);
  float rs = rsqrtf(sq * (1.f / 768.f) - mu * mu + 1e-5f);
  bf16* op = out + (size_t)row * DD;
#pragma unroll
  for (int i = 0; i < 3; i++) {
    int col = lane * 4 + i * 256;
    float4 g4 = *(const float4*)(lng + col);
    float4 b4 = *(const float4*)(lnb + col);
    bf16x4 pk;
    pk.v[0] = (bf16)((v[i].x - mu) * rs * g4.x + b4.x);
    pk.v[1] = (bf16)((v[i].y - mu) * rs * g4.y + b4.y);
    pk.v[2] = (bf16)((v[i].z - mu) * rs * g4.z + b4.z);
    pk.v[3] = (bf16)((v[i].w - mu) * rs * g4.w + b4.w);
    *(bf16x4*)(op + col) = pk;
  }
}

// ---------------- transpose + f32->bf16 weight conversion ----------------
__launch_bounds__(256)
__global__ void tcvt_k(const float* __restrict__ in, bf16* __restrict__ out,
                       int Ksrc, int ldin, int ldout,
                       size_t sIn, size_t sOut, int mode, const float* __restrict__ alphap) {
  __shared__ float tl[32][33];
  int z = blockIdx.z;
  const float* src = in + (size_t)z * sIn;
  bf16* dst = out + (size_t)z * sOut;
  int n0 = blockIdx.x * 32, k0 = blockIdx.y * 32;
  int tx = threadIdx.x, ty = threadIdx.y;
  int n = n0 + tx;
  int c = n; bool nv = true;
  if (mode == 1) {
    if (n < 48)       c = n;
    else if (n < 64)  nv = false;
    else if (n < 192) c = n - 16;
    else              nv = false;
  }
  float scale = 1.f;
  if (mode == 2) {
    float a0 = alphap[0], a1 = alphap[1], a2 = alphap[2];
    float mx = fmaxf(a0, fmaxf(a1, a2));
    float e0 = __expf(a0 - mx), e1 = __expf(a1 - mx), e2 = __expf(a2 - mx);
    scale = ((z == 0) ? e0 : (z == 1) ? e1 : e2) / (e0 + e1 + e2);
  }
#pragma unroll
  for (int i = 0; i < 32; i += 8) {
    int k = k0 + ty + i;
    float v = (nv && k < Ksrc) ? src[(size_t)k * ldin + c] : 0.f;
    tl[ty + i][tx] = v * scale;
  }
  __syncthreads();
#pragma unroll
  for (int i = 0; i < 32; i += 8) {
    dst[(size_t)(n0 + ty + i) * ldout + (k0 + tx)] = (bf16)tl[tx][ty + i];
  }
}

// ---------------- causal depthwise conv (K=4) + SiLU, 8 channels/thread ----------------
__launch_bounds__(256)
__global__ void conv_silu_k(const bf16* __restrict__ xp, const float* __restrict__ cw,
                            const float* __restrict__ cb, bf16* __restrict__ xs) {
  long i = ((long)blockIdx.x * 256 + threadIdx.x) * 8;   // elem index, 8 channels
  int  c  = (int)(i % DIN);
  long rl = i / DIN;                                     // (e*B + b)*L + l
  int  l  = (int)(rl & (LL - 1));
  int  e  = (int)(rl >> 12);                             // B*L = 4096
  const float* wp  = cw + (size_t)e * DIN * 4 + (size_t)c * 4;
  const float* cbp = cb + (size_t)e * DIN + c;
  float acc[8];
#pragma unroll
  for (int j = 0; j < 8; j++) acc[j] = cbp[j];
#pragma unroll
  for (int tap = 0; tap < 4; tap++) {
    if (l - 3 + tap >= 0) {
      s16x8 xv = *(const s16x8*)(const void*)(xp + (rl + tap - 3) * DIN + c);
#pragma unroll
      for (int j = 0; j < 8; j++)
        acc[j] = fmaf(bf2f((u16)xv[j]), wp[j * 4 + tap], acc[j]);
    }
  }
  bf16x8 pk;
#pragma unroll
  for (int j = 0; j < 8; j++) pk.v[j] = (bf16)siluf(acc[j]);
  *(bf16x8*)(xs + rl * DIN + c) = pk;
}

// ---------------- bf16 MFMA GEMM (R5 measured-best reg-staged version) ----------------
// MODE 0: xz GEMM  -> o0=xp bf16 (n<DIN), o1=silu(z) bf16
// MODE 1: dbl GEMM -> gc<64 -> dblp bf16 (ld 64); gc 64..191 -> dblf f32 [M][128]
// MODE 2: dt GEMM  -> o0=softplus(acc + bias[gc]) bf16 (row-major [M][DIN])
// MODE 3: out GEMM -> atomicAdd into outp (W_out pre-scaled by softmax(alpha))
template<int MODE>
__launch_bounds__(256)
__global__ void mfma_gemm_k(const bf16* __restrict__ A, const bf16* __restrict__ Bt,
                            int Kdim, int lda,
                            size_t sA, size_t sB, size_t sO,
                            bf16* __restrict__ o0, bf16* __restrict__ o1,
                            const float* __restrict__ bias,
                            float* __restrict__ outp) {
  __shared__ short As[128 * 32];
  __shared__ short Bs[128 * 32];
  int z = blockIdx.z;
  A  += (size_t)z * sA;
  Bt += (size_t)z * sB;
  if (o0) o0 += (size_t)z * sO;
  if (o1) o1 += (size_t)z * sO;
  if constexpr (MODE == 1) outp += (size_t)z * (size_t)MM * 128;
  const float* bz = (MODE == 2) ? bias + (size_t)z * DIN : bias;

  int t = threadIdx.x;
  int l = t & 63, w = t >> 6;
  int wr = w >> 1, wc = w & 1;
  int n0 = blockIdx.x * 128, r0 = blockIdx.y * 128;

  int row = t >> 2, c3 = t & 3, col = c3 * 8;
  int plo = ((c3 & 1) ? 16 : 0) + ((c3 & 2) ? 4 : 0);   // k-permuted LDS slot
  int lrow = (l & 15) * 32 + (l >> 4) * 8;

  f32x4 acc[4][4] = {};

  for (int k0 = 0; k0 < Kdim; k0 += 32) {
    s16x8 va0 = *(const s16x8*)(const void*)(A  + (size_t)(r0 + row)      * lda  + k0 + col);
    s16x8 va1 = *(const s16x8*)(const void*)(A  + (size_t)(r0 + row + 64) * lda  + k0 + col);
    s16x8 vb0 = *(const s16x8*)(const void*)(Bt + (size_t)(n0 + row)      * Kdim + k0 + col);
    s16x8 vb1 = *(const s16x8*)(const void*)(Bt + (size_t)(n0 + row + 64) * Kdim + k0 + col);
    __syncthreads();   // previous iteration's ds_reads done
    *(s16x4*)(As + row * 32 + plo)          = __builtin_shufflevector(va0, va0, 0, 1, 2, 3);
    *(s16x4*)(As + row * 32 + plo + 8)      = __builtin_shufflevector(va0, va0, 4, 5, 6, 7);
    *(s16x4*)(As + (row + 64) * 32 + plo)     = __builtin_shufflevector(va1, va1, 0, 1, 2, 3);
    *(s16x4*)(As + (row + 64) * 32 + plo + 8) = __builtin_shufflevector(va1, va1, 4, 5, 6, 7);
    *(s16x4*)(Bs + row * 32 + plo)          = __builtin_shufflevector(vb0, vb0, 0, 1, 2, 3);
    *(s16x4*)(Bs + row * 32 + plo + 8)      = __builtin_shufflevector(vb0, vb0, 4, 5, 6, 7);
    *(s16x4*)(Bs + (row + 64) * 32 + plo)     = __builtin_shufflevector(vb1, vb1, 0, 1, 2, 3);
    *(s16x4*)(Bs + (row + 64) * 32 + plo + 8) = __builtin_shufflevector(vb1, vb1, 4, 5, 6, 7);
    __syncthreads();
    s16x8 af[4], bfv[4];
#pragma unroll
    for (int m = 0; m < 4; m++) af[m]  = *(const s16x8*)(As + (wr * 64 + m * 16) * 32 + lrow);
#pragma unroll
    for (int n = 0; n < 4; n++) bfv[n] = *(const s16x8*)(Bs + (wc * 64 + n * 16) * 32 + lrow);
#pragma unroll
    for (int m = 0; m < 4; m++)
#pragma unroll
      for (int n = 0; n < 4; n++)
        acc[m][n] = __builtin_amdgcn_mfma_f32_16x16x32_bf16(af[m], bfv[n], acc[m][n], 0, 0, 0);
  }

  int rb = r0 + wr * 64 + ((l >> 4) << 2);
  int cb = n0 + wc * 64 + (l & 15);
#pragma unroll
  for (int m = 0; m < 4; m++)
#pragma unroll
    for (int n = 0; n < 4; n++)
#pragma unroll
      for (int r = 0; r < 4; r++) {
        int gr = rb + m * 16 + r;
        int gc = cb + n * 16;
        float v = acc[m][n][r];
        if constexpr (MODE == 0) {
          if (n0 < DIN) o0[(size_t)gr * DIN + gc] = (bf16)v;
          else          o1[(size_t)gr * DIN + (gc - DIN)] = (bf16)siluf(v);
        } else if constexpr (MODE == 1) {
          if (gc < 64)       o0[(size_t)gr * 64 + gc] = (bf16)v;
          else if (gc < 192) outp[(size_t)gr * 128 + (gc - 64)] = v;
        } else if constexpr (MODE == 2) {
          o0[(size_t)gr * DIN + gc] = (bf16)softplusf(v + bz[gc]);
        } else {
          atomicAdd(&outp[(size_t)gr * DD + gc], v);
        }
      }
}

// ---------------- out = base (init before atomic accumulation) ----------------
__launch_bounds__(256)
__global__ void copy4_k(const float* __restrict__ s, float* __restrict__ d, int n4) {
  int i = blockIdx.x * 256 + threadIdx.x;
  if (i < n4) ((float4*)d)[i] = ((const float4*)s)[i];
}

// ---------------- chunked selective scan, pass 1: local scans ----------------
// 4 lanes/channel x 16 states/lane x 4 L-chunks. Each chunk scans 256 steps
// with h0=0, writing y_local (gated, incl. u*dskip) in place over xs. Chunks
// 0..2 also store final h (bf16) and sum(dt) for the fixup pass. Whole wave
// shares one (e,b,l) B/C row (broadcast-friendly). u prefetched 1 step ahead
// (only xs aliases the store); last-iter prefetch overruns into gws - safe.
__launch_bounds__(256)
__global__ void scan_local_k(const bf16* __restrict__ dtb, bf16* __restrict__ xsb,
                             const bf16* __restrict__ gb, const float* __restrict__ dblf,
                             const float* __restrict__ A_log, const float* __restrict__ Dsk,
                             bf16* __restrict__ hf, float* __restrict__ Ssum) {
  int gt = blockIdx.x * 256 + threadIdx.x;
  int sg2  = gt & 3;            // states [sg2*16, sg2*16+16)
  int rest = gt >> 2;
  int ch    = rest % NCH;       // eb*DIN + d
  int chunk = rest / NCH;
  int d  = ch % DIN;
  int eb = ch / DIN;
  int e  = eb >> 2;             // B == 4

  const float LOG2E = 1.44269504088896f;
  float A2[16], h[16];
  const float4* Ap = (const float4*)(A_log + ((size_t)e * DIN + d) * DSN + sg2 * 16);
#pragma unroll
  for (int i = 0; i < 4; i++) {
    float4 a = Ap[i];
    A2[4 * i + 0] = -__expf(a.x) * LOG2E;
    A2[4 * i + 1] = -__expf(a.y) * LOG2E;
    A2[4 * i + 2] = -__expf(a.z) * LOG2E;
    A2[4 * i + 3] = -__expf(a.w) * LOG2E;
    h[4 * i] = h[4 * i + 1] = h[4 * i + 2] = h[4 * i + 3] = 0.f;
  }
  float dskip = Dsk[(size_t)e * DIN + d];

  int l0 = chunk * CL;
  unsigned idx = (unsigned)eb * (LL * DIN) + (unsigned)(l0 * DIN) + (unsigned)d;
  const float* bp = dblf + ((size_t)eb * LL + l0) * 128 + sg2 * 16;

  float S = 0.f;
  float u = (float)xsb[idx];   // prefetch u (step 0)

  for (int t = 0; t < CL; ++t) {
    float dtv = (float)dtb[idx];
    float gv  = (float)gb[idx];
    float un  = (float)xsb[idx + DIN];     // next-step u (hoistable: issued pre-store)
    float Bf[16], Cf[16];
    *(float4*)&Bf[0]  = *(const float4*)(bp);
    *(float4*)&Bf[4]  = *(const float4*)(bp + 4);
    *(float4*)&Bf[8]  = *(const float4*)(bp + 8);
    *(float4*)&Bf[12] = *(const float4*)(bp + 12);
    *(float4*)&Cf[0]  = *(const float4*)(bp + 64);
    *(float4*)&Cf[4]  = *(const float4*)(bp + 68);
    *(float4*)&Cf[8]  = *(const float4*)(bp + 72);
    *(float4*)&Cf[12] = *(const float4*)(bp + 76);

    S += dtv;
    float du = dtv * u;
    float p = 0.f;
#pragma unroll
    for (int s = 0; s < 16; ++s) {
      float dA = __builtin_amdgcn_exp2f(dtv * A2[s]);
      h[s] = fmaf(dA, h[s], du * Bf[s]);
      p = fmaf(h[s], Cf[s], p);
    }
    p = dpp_add<0xB1>(p);   // quad_perm(1,0,3,2)
    p = dpp_add<0x4E>(p);   // quad_perm(2,3,0,1)
    if (sg2 == 0) {
      xsb[idx] = (bf16)(fmaf(u, dskip, p) * gv);   // y_local (gated) over xs
    }
    idx += DIN; bp += 128; u = un;
  }

  if (chunk < NC - 1) {
    bf16* hp = hf + (((size_t)chunk * NCH + ch) << 6) + sg2 * 16;
    bf16x8 p0, p1;
#pragma unroll
    for (int j = 0; j < 8; j++) { p0.v[j] = (bf16)h[j]; p1.v[j] = (bf16)h[8 + j]; }
    *(bf16x8*)hp       = p0;
    *(bf16x8*)(hp + 8) = p1;
    if (sg2 == 0) Ssum[chunk * NCH + ch] = S;
  }
}

// ---------------- chunked selective scan, pass 2: boundary fixup ----------------
// For chunk c in 1..3: combine entering state H_c = hf_{c-1} + P_{c-1}*H_{c-1}
// (P_j = exp2(A2*S_j), Horner over stored chunk finals), then add the
// homogeneous correction y_l += (C_l . G_l) * g_l with G decaying: G *= dA_l.
__launch_bounds__(256)
__global__ void scan_fix_k(const bf16* __restrict__ dtb, bf16* __restrict__ xsb,
                           const bf16* __restrict__ gb, const float* __restrict__ dblf,
                           const float* __restrict__ A_log,
                           const bf16* __restrict__ hf, const float* __restrict__ Ssum) {
  int gt = blockIdx.x * 256 + threadIdx.x;
  int sg2  = gt & 3;
  int rest = gt >> 2;
  int ch = rest % NCH;
  int cf = 1 + rest / NCH;      // chunk 1..3
  int d  = ch % DIN;
  int eb = ch / DIN;
  int e  = eb >> 2;

  const float LOG2E = 1.44269504088896f;
  float A2[16];
  const float4* Ap = (const float4*)(A_log + ((size_t)e * DIN + d) * DSN + sg2 * 16);
#pragma unroll
  for (int i = 0; i < 4; i++) {
    float4 a = Ap[i];
    A2[4 * i + 0] = -__expf(a.x) * LOG2E;
    A2[4 * i + 1] = -__expf(a.y) * LOG2E;
    A2[4 * i + 2] = -__expf(a.z) * LOG2E;
    A2[4 * i + 3] = -__expf(a.w) * LOG2E;
  }

  // entering state G = H_cf (Horner combine of stored chunk finals)
  float G[16];
  {
    const bf16* hp = hf + ((size_t)ch << 6) + sg2 * 16;   // chunk 0
#pragma unroll
    for (int s = 0; s < 16; ++s) G[s] = (float)hp[s];
  }
  for (int j = 1; j < cf; ++j) {
    float Sj = Ssum[j * NCH + ch];
    const bf16* hp = hf + (((size_t)j * NCH + ch) << 6) + sg2 * 16;
#pragma unroll
    for (int s = 0; s < 16; ++s)
      G[s] = fmaf(__builtin_amdgcn_exp2f(A2[s] * Sj), G[s], (float)hp[s]);
  }

  int l0 = cf * CL;
  unsigned idx = (unsigned)eb * (LL * DIN) + (unsigned)(l0 * DIN) + (unsigned)d;
  const float* bp = dblf + ((size_t)eb * LL + l0) * 128 + sg2 * 16;

  for (int t = 0; t < CL; ++t) {
    float dtv = (float)dtb[idx];
    float Cf[16];
    *(float4*)&Cf[0]  = *(const float4*)(bp + 64);
    *(float4*)&Cf[4]  = *(const float4*)(bp + 68);
    *(float4*)&Cf[8]  = *(const float4*)(bp + 72);
    *(float4*)&Cf[12] = *(const float4*)(bp + 76);
    float p = 0.f;
#pragma unroll
    for (int s = 0; s < 16; ++s) {
      G[s] *= __builtin_amdgcn_exp2f(dtv * A2[s]);
      p = fmaf(G[s], Cf[s], p);
    }
    p = dpp_add<0xB1>(p);
    p = dpp_add<0x4E>(p);
    if (sg2 == 0) {
      float gv = (float)gb[idx];
      float y  = (float)xsb[idx];
      xsb[idx] = (bf16)fmaf(p, gv, y);   // y += correction * gate
    }
    idx += DIN; bp += 128;
  }
}

extern "C" void kernel_launch(void* const* d_in, const int* in_sizes, int n_in,
                              void* d_out, int out_size, void* d_ws, size_t ws_size,
                              hipStream_t stream) {
  const float* base   = (const float*)d_in[0];
  const float* per_ch = (const float*)d_in[1];
  const float* alpha  = (const float*)d_in[2];
  const float* ln_g   = (const float*)d_in[3];
  const float* ln_b   = (const float*)d_in[4];
  const float* W_in   = (const float*)d_in[5];
  const float* conv_w = (const float*)d_in[6];
  const float* conv_b = (const float*)d_in[7];
  const float* W_x    = (const float*)d_in[8];
  const float* W_dt   = (const float*)d_in[9];
  const float* b_dt   = (const float*)d_in[10];
  const float* A_log  = (const float*)d_in[11];
  const float* D_skip = (const float*)d_in[12];
  const float* W_out  = (const float*)d_in[13];
  float* out = (float*)d_out;
  (void)in_sizes; (void)n_in; (void)out_size; (void)ws_size;

  // Workspace layout (131.9 MB), lifetime overlays:
  //  R1 [37.75M]: Abf (18.87M) -> xs (row-major) -> y (scan writes in-place)
  //  R2 [37.75M]: g = silu(z)
  //  R3 [37.75M]: xp -> dt (row-major [M][DIN])
  //  R4 [14.16M]: W_inT -> [WoutT 7.08M | dblf 6.29M | Ssum 221KB in spare]
  //  R5 [ 2.36M]: W_xT ;  R6 [0.59M]: W_dtT ;  R7 [1.57M]: dblp bf16 (ld 64)
  //  hf (chunk finals, bf16 [3][NCH][64] = 7.08M) lives in d_out before copy4.
  char* ws = (char*)d_ws;
  const size_t R = (size_t)EXP * MM * DIN * 2;            // 37,748,736
  bf16* Abf   = (bf16*)ws;
  bf16* xsws  = (bf16*)ws;
  bf16* gws   = (bf16*)(ws + R);
  bf16* dtws  = (bf16*)(ws + 2 * R);
  char* R4    = ws + 3 * R;
  bf16*  WinT  = (bf16*)R4;
  bf16*  WoutT = (bf16*)R4;                               // overlays WinT after MODE0
  float* dblf  = (float*)(R4 + 7077888);                  // E*M*128 f32 = 6.29M
  float* Ssum  = (float*)(R4 + 13369344);                 // 3*NCH f32 = 221KB (R4 spare)
  bf16* WxT   = (bf16*)(ws + 3 * R + 14155776);
  bf16* WdtT  = (bf16*)(ws + 3 * R + 14155776 + 2359296);
  bf16* dblp  = (bf16*)(ws + 3 * R + 14155776 + 2359296 + 589824);
  bf16* hf    = (bf16*)d_out;                             // scratch until copy4

  dim3 blk2(32, 8);

  // prep: LN->bf16, weight transposes (bf16, B^T layout)
  ln_apply_k<<<EXP * BB * LL / 4, 256, 0, stream>>>(per_ch, ln_g, ln_b, Abf);
  tcvt_k<<<dim3(96, 24, EXP), blk2, 0, stream>>>(W_in, WinT, 768, 3072, 768,
        (size_t)768 * 3072, (size_t)3072 * 768, 0, nullptr);
  tcvt_k<<<dim3(8, 48, EXP), blk2, 0, stream>>>(W_x, WxT, 1536, 176, 1536,
        (size_t)1536 * 176, (size_t)256 * 1536, 1, nullptr);
  tcvt_k<<<dim3(48, 2, EXP), blk2, 0, stream>>>(W_dt, WdtT, 48, 1536, 64,
        (size_t)48 * 1536, (size_t)1536 * 64, 0, nullptr);

  // xz = Abf @ W_in -> xp (dtws), silu(z) (gws)
  mfma_gemm_k<0><<<dim3(24, 32, EXP), 256, 0, stream>>>(Abf, WinT, 768, DD,
        (size_t)MM * DD, (size_t)3072 * 768, (size_t)MM * DIN,
        dtws, gws, nullptr, nullptr);

  // W_outT (pre-scaled by softmax(alpha)) -- overlays W_inT, safe after MODE0
  tcvt_k<<<dim3(24, 48, EXP), blk2, 0, stream>>>(W_out, WoutT, 1536, 768, 1536,
        (size_t)1536 * 768, (size_t)768 * 1536, 2, alpha);

  // causal conv + silu -> xs (overlays Abf, safe after MODE0)
  conv_silu_k<<<EXP * BB * LL * DIN / 8 / 256, 256, 0, stream>>>(dtws, conv_w, conv_b, xsws);

  // dbl = xs @ W_x: dt cols -> dblp (bf16, ld 64); B|C -> dblf f32 row-major [M][128]
  mfma_gemm_k<1><<<dim3(2, 32, EXP), 256, 0, stream>>>(xsws, WxT, 1536, DIN,
        (size_t)MM * DIN, (size_t)256 * 1536, (size_t)MM * 64,
        dblp, nullptr, nullptr, dblf);

  // dt = softplus(dblp @ W_dt + b_dt) -> dtws
  mfma_gemm_k<2><<<dim3(12, 32, EXP), 256, 0, stream>>>(dblp, WdtT, 64, 64,
        (size_t)MM * 64, (size_t)1536 * 64, (size_t)MM * DIN,
        dtws, nullptr, b_dt, nullptr);

  // chunked scan: local pass (all 4 chunks in parallel), then boundary fixup
  scan_local_k<<<NCH * 4 * NC / 256, 256, 0, stream>>>(
      dtws, xsws, gws, dblf, A_log, D_skip, hf, Ssum);
  scan_fix_k<<<NCH * 4 * (NC - 1) / 256, 256, 0, stream>>>(
      dtws, xsws, gws, dblf, A_log, hf, Ssum);

  // out = base (after hf scratch is dead); out += sum_e y_e @ (w_e*W_out_e)
  copy4_k<<<MM * DD / 4 / 256, 256, 0, stream>>>(base, out, MM * DD / 4);
  mfma_gemm_k<3><<<dim3(6, 32, EXP), 256, 0, stream>>>(xsws, WoutT, 1536, DIN,
        (size_t)MM * DIN, (size_t)768 * 1536, 0,
        nullptr, nullptr, nullptr, out);
}

// Round 10
// 1323.607 us; speedup vs baseline: 1.0020x; 1.0020x over previous
//
#include <hip/hip_runtime.h>
#include <hip/hip_bf16.h>

typedef __hip_bfloat16 bf16;
typedef unsigned short u16;
typedef __attribute__((ext_vector_type(8))) short s16x8;
typedef __attribute__((ext_vector_type(4))) short s16x4;
typedef __attribute__((ext_vector_type(4))) float f32x4;

#define EXP 3
#define BB  4
#define LL  1024
#define DD  768
#define DSN 64
#define DIN 1536
#define DTR 48
#define MM  4096       // B*L rows per expert
#define NCH 18432      // EXP*BB*DIN channels
#define NC  4          // L-chunks
#define CL  256        // steps per chunk

struct alignas(8)  bf16x4 { bf16 v[4]; };
struct alignas(16) bf16x8 { bf16 v[8]; };

__device__ __forceinline__ float siluf(float x) { return x / (1.f + __expf(-x)); }
__device__ __forceinline__ float softplusf(float x) { return (x > 15.f) ? x : log1pf(__expf(x)); }
__device__ __forceinline__ float bf2f(u16 h) { union { unsigned u; float f; } x; x.u = ((unsigned)h) << 16; return x.f; }

// DPP add: x + perm(x). quad_perm(1,0,3,2)=0xB1, quad_perm(2,3,0,1)=0x4E ->
// 4-lane allreduce in two steps (quad groups never cross channel boundaries).
template <int CTRL>
__device__ __forceinline__ float dpp_add(float x) {
  int y = __builtin_amdgcn_update_dpp(0, __float_as_int(x), CTRL, 0xf, 0xf, true);
  return x + __int_as_float(y);
}

// ---------------- LayerNorm apply + bf16 convert: per_ch -> Abf ----------------
__launch_bounds__(256)
__global__ void ln_apply_k(const float* __restrict__ pc, const float* __restrict__ lng,
                           const float* __restrict__ lnb, bf16* __restrict__ out) {
  int row  = blockIdx.x * 4 + (threadIdx.x >> 6);
  int lane = threadIdx.x & 63;
  const float* x = pc + (size_t)row * DD;
  float4 v[3];
  float s = 0.f, sq = 0.f;
#pragma unroll
  for (int i = 0; i < 3; i++) {
    v[i] = *(const float4*)(x + lane * 4 + i * 256);
    s  += v[i].x + v[i].y + v[i].z + v[i].w;
    sq += v[i].x * v[i].x + v[i].y * v[i].y + v[i].z * v[i].z + v[i].w * v[i].w;
  }
#pragma unroll
  for (int o = 1; o < 64; o <<= 1) { s += __shfl_xor(s, o); sq += __shfl_xor(sq, o); }
  float mu = s * (1.f / 768.f);
  float rs = rsqrtf(sq * (1.f / 768.f) - mu * mu + 1e-5f);
  bf16* op = out + (size_t)row * DD;
#pragma unroll
  for (int i = 0; i < 3; i++) {
    int col = lane * 4 + i * 256;
    float4 g4 = *(const float4*)(lng + col);
    float4 b4 = *(const float4*)(lnb + col);
    bf16x4 pk;
    pk.v[0] = (bf16)((v[i].x - mu) * rs * g4.x + b4.x);
    pk.v[1] = (bf16)((v[i].y - mu) * rs * g4.y + b4.y);
    pk.v[2] = (bf16)((v[i].z - mu) * rs * g4.z + b4.z);
    pk.v[3] = (bf16)((v[i].w - mu) * rs * g4.w + b4.w);
    *(bf16x4*)(op + col) = pk;
  }
}

// ---------------- transpose + f32->bf16 weight conversion ----------------
__launch_bounds__(256)
__global__ void tcvt_k(const float* __restrict__ in, bf16* __restrict__ out,
                       int Ksrc, int ldin, int ldout,
                       size_t sIn, size_t sOut, int mode, const float* __restrict__ alphap) {
  __shared__ float tl[32][33];
  int z = blockIdx.z;
  const float* src = in + (size_t)z * sIn;
  bf16* dst = out + (size_t)z * sOut;
  int n0 = blockIdx.x * 32, k0 = blockIdx.y * 32;
  int tx = threadIdx.x, ty = threadIdx.y;
  int n = n0 + tx;
  int c = n; bool nv = true;
  if (mode == 1) {
    if (n < 48)       c = n;
    else if (n < 64)  nv = false;
    else if (n < 192) c = n - 16;
    else              nv = false;
  }
  float scale = 1.f;
  if (mode == 2) {
    float a0 = alphap[0], a1 = alphap[1], a2 = alphap[2];
    float mx = fmaxf(a0, fmaxf(a1, a2));
    float e0 = __expf(a0 - mx), e1 = __expf(a1 - mx), e2 = __expf(a2 - mx);
    scale = ((z == 0) ? e0 : (z == 1) ? e1 : e2) / (e0 + e1 + e2);
  }
#pragma unroll
  for (int i = 0; i < 32; i += 8) {
    int k = k0 + ty + i;
    float v = (nv && k < Ksrc) ? src[(size_t)k * ldin + c] : 0.f;
    tl[ty + i][tx] = v * scale;
  }
  __syncthreads();
#pragma unroll
  for (int i = 0; i < 32; i += 8) {
    dst[(size_t)(n0 + ty + i) * ldout + (k0 + tx)] = (bf16)tl[tx][ty + i];
  }
}

// ---------------- causal depthwise conv (K=4) + SiLU, 8 channels/thread ----------------
__launch_bounds__(256)
__global__ void conv_silu_k(const bf16* __restrict__ xp, const float* __restrict__ cw,
                            const float* __restrict__ cb, bf16* __restrict__ xs) {
  long i = ((long)blockIdx.x * 256 + threadIdx.x) * 8;   // elem index, 8 channels
  int  c  = (int)(i % DIN);
  long rl = i / DIN;                                     // (e*B + b)*L + l
  int  l  = (int)(rl & (LL - 1));
  int  e  = (int)(rl >> 12);                             // B*L = 4096
  const float* wp  = cw + (size_t)e * DIN * 4 + (size_t)c * 4;
  const float* cbp = cb + (size_t)e * DIN + c;
  float acc[8];
#pragma unroll
  for (int j = 0; j < 8; j++) acc[j] = cbp[j];
#pragma unroll
  for (int tap = 0; tap < 4; tap++) {
    if (l - 3 + tap >= 0) {
      s16x8 xv = *(const s16x8*)(const void*)(xp + (rl + tap - 3) * DIN + c);
#pragma unroll
      for (int j = 0; j < 8; j++)
        acc[j] = fmaf(bf2f((u16)xv[j]), wp[j * 4 + tap], acc[j]);
    }
  }
  bf16x8 pk;
#pragma unroll
  for (int j = 0; j < 8; j++) pk.v[j] = (bf16)siluf(acc[j]);
  *(bf16x8*)(xs + rl * DIN + c) = pk;
}

// ---------------- bf16 MFMA GEMM (R5 measured-best reg-staged version) ----------------
// MODE 0: xz GEMM  -> o0=xp bf16 (n<DIN), o1=silu(z) bf16
// MODE 1: dbl GEMM -> gc<64 -> dblp bf16 (ld 64); gc 64..191 -> dblf f32 [M][128]
// MODE 2: dt GEMM  -> o0=softplus(acc + bias[gc]) bf16 (row-major [M][DIN])
// MODE 3: out GEMM -> atomicAdd into outp (W_out pre-scaled by softmax(alpha))
template<int MODE>
__launch_bounds__(256)
__global__ void mfma_gemm_k(const bf16* __restrict__ A, const bf16* __restrict__ Bt,
                            int Kdim, int lda,
                            size_t sA, size_t sB, size_t sO,
                            bf16* __restrict__ o0, bf16* __restrict__ o1,
                            const float* __restrict__ bias,
                            float* __restrict__ outp) {
  __shared__ short As[128 * 32];
  __shared__ short Bs[128 * 32];
  int z = blockIdx.z;
  A  += (size_t)z * sA;
  Bt += (size_t)z * sB;
  if (o0) o0 += (size_t)z * sO;
  if (o1) o1 += (size_t)z * sO;
  if constexpr (MODE == 1) outp += (size_t)z * (size_t)MM * 128;
  const float* bz = (MODE == 2) ? bias + (size_t)z * DIN : bias;

  int t = threadIdx.x;
  int l = t & 63, w = t >> 6;
  int wr = w >> 1, wc = w & 1;
  int n0 = blockIdx.x * 128, r0 = blockIdx.y * 128;

  int row = t >> 2, c3 = t & 3, col = c3 * 8;
  int plo = ((c3 & 1) ? 16 : 0) + ((c3 & 2) ? 4 : 0);   // k-permuted LDS slot
  int lrow = (l & 15) * 32 + (l >> 4) * 8;

  f32x4 acc[4][4] = {};

  for (int k0 = 0; k0 < Kdim; k0 += 32) {
    s16x8 va0 = *(const s16x8*)(const void*)(A  + (size_t)(r0 + row)      * lda  + k0 + col);
    s16x8 va1 = *(const s16x8*)(const void*)(A  + (size_t)(r0 + row + 64) * lda  + k0 + col);
    s16x8 vb0 = *(const s16x8*)(const void*)(Bt + (size_t)(n0 + row)      * Kdim + k0 + col);
    s16x8 vb1 = *(const s16x8*)(const void*)(Bt + (size_t)(n0 + row + 64) * Kdim + k0 + col);
    __syncthreads();   // previous iteration's ds_reads done
    *(s16x4*)(As + row * 32 + plo)          = __builtin_shufflevector(va0, va0, 0, 1, 2, 3);
    *(s16x4*)(As + row * 32 + plo + 8)      = __builtin_shufflevector(va0, va0, 4, 5, 6, 7);
    *(s16x4*)(As + (row + 64) * 32 + plo)     = __builtin_shufflevector(va1, va1, 0, 1, 2, 3);
    *(s16x4*)(As + (row + 64) * 32 + plo + 8) = __builtin_shufflevector(va1, va1, 4, 5, 6, 7);
    *(s16x4*)(Bs + row * 32 + plo)          = __builtin_shufflevector(vb0, vb0, 0, 1, 2, 3);
    *(s16x4*)(Bs + row * 32 + plo + 8)      = __builtin_shufflevector(vb0, vb0, 4, 5, 6, 7);
    *(s16x4*)(Bs + (row + 64) * 32 + plo)     = __builtin_shufflevector(vb1, vb1, 0, 1, 2, 3);
    *(s16x4*)(Bs + (row + 64) * 32 + plo + 8) = __builtin_shufflevector(vb1, vb1, 4, 5, 6, 7);
    __syncthreads();
    s16x8 af[4], bfv[4];
#pragma unroll
    for (int m = 0; m < 4; m++) af[m]  = *(const s16x8*)(As + (wr * 64 + m * 16) * 32 + lrow);
#pragma unroll
    for (int n = 0; n < 4; n++) bfv[n] = *(const s16x8*)(Bs + (wc * 64 + n * 16) * 32 + lrow);
#pragma unroll
    for (int m = 0; m < 4; m++)
#pragma unroll
      for (int n = 0; n < 4; n++)
        acc[m][n] = __builtin_amdgcn_mfma_f32_16x16x32_bf16(af[m], bfv[n], acc[m][n], 0, 0, 0);
  }

  int rb = r0 + wr * 64 + ((l >> 4) << 2);
  int cb = n0 + wc * 64 + (l & 15);
#pragma unroll
  for (int m = 0; m < 4; m++)
#pragma unroll
    for (int n = 0; n < 4; n++)
#pragma unroll
      for (int r = 0; r < 4; r++) {
        int gr = rb + m * 16 + r;
        int gc = cb + n * 16;
        float v = acc[m][n][r];
        if constexpr (MODE == 0) {
          if (n0 < DIN) o0[(size_t)gr * DIN + gc] = (bf16)v;
          else          o1[(size_t)gr * DIN + (gc - DIN)] = (bf16)siluf(v);
        } else if constexpr (MODE == 1) {
          if (gc < 64)       o0[(size_t)gr * 64 + gc] = (bf16)v;
          else if (gc < 192) outp[(size_t)gr * 128 + (gc - 64)] = v;
        } else if constexpr (MODE == 2) {
          o0[(size_t)gr * DIN + gc] = (bf16)softplusf(v + bz[gc]);
        } else {
          atomicAdd(&outp[(size_t)gr * DD + gc], v);
        }
      }
}

// ---------------- out = base (init before atomic accumulation) ----------------
__launch_bounds__(256)
__global__ void copy4_k(const float* __restrict__ s, float* __restrict__ d, int n4) {
  int i = blockIdx.x * 256 + threadIdx.x;
  if (i < n4) ((float4*)d)[i] = ((const float4*)s)[i];
}

#define LOAD16(DST, SRC)                              \
  { *(float4*)&DST[0]  = *(const float4*)((SRC));     \
    *(float4*)&DST[4]  = *(const float4*)((SRC) + 4); \
    *(float4*)&DST[8]  = *(const float4*)((SRC) + 8); \
    *(float4*)&DST[12] = *(const float4*)((SRC) + 12); }

// ---------------- chunked selective scan, pass 1: local scans ----------------
// 4 lanes/channel x 16 states/lane x 4 L-chunks, R5-style FULL depth-1
// prefetch (dt/g/u/B/C) via 2-step ping-pong (no register rotation). Final
// prefetch overruns into the adjacent ws region / next chunk - value unused.
__launch_bounds__(256)
__global__ void scan_local_k(const bf16* __restrict__ dtb, bf16* __restrict__ xsb,
                             const bf16* __restrict__ gb, const float* __restrict__ dblf,
                             const float* __restrict__ A_log, const float* __restrict__ Dsk,
                             bf16* __restrict__ hf, float* __restrict__ Ssum) {
  int gt = blockIdx.x * 256 + threadIdx.x;
  int sg2  = gt & 3;            // states [sg2*16, sg2*16+16)
  int rest = gt >> 2;
  int ch    = rest % NCH;       // eb*DIN + d
  int chunk = rest / NCH;
  int d  = ch % DIN;
  int eb = ch / DIN;
  int e  = eb >> 2;             // B == 4

  const float LOG2E = 1.44269504088896f;
  float A2[16], h[16];
  const float4* Ap = (const float4*)(A_log + ((size_t)e * DIN + d) * DSN + sg2 * 16);
#pragma unroll
  for (int i = 0; i < 4; i++) {
    float4 a = Ap[i];
    A2[4 * i + 0] = -__expf(a.x) * LOG2E;
    A2[4 * i + 1] = -__expf(a.y) * LOG2E;
    A2[4 * i + 2] = -__expf(a.z) * LOG2E;
    A2[4 * i + 3] = -__expf(a.w) * LOG2E;
    h[4 * i] = h[4 * i + 1] = h[4 * i + 2] = h[4 * i + 3] = 0.f;
  }
  float dskip = Dsk[(size_t)e * DIN + d];

  int l0 = chunk * CL;
  unsigned idx = (unsigned)eb * (LL * DIN) + (unsigned)(l0 * DIN) + (unsigned)d;
  const float* bp = dblf + ((size_t)eb * LL + l0) * 128 + sg2 * 16;

  float S = 0.f;
  float dt0, g0, u0, dt1, g1, u1;
  float B0[16], C0[16], B1[16], C1[16];

  // prefetch step 0 into buf0
  dt0 = (float)dtb[idx]; g0 = (float)gb[idx]; u0 = (float)xsb[idx];
  LOAD16(B0, bp) LOAD16(C0, bp + 64)

#define LSTEP(DT, GV, UU, BF, CF)                                          \
  {                                                                        \
    S += (DT);                                                             \
    float du = (DT) * (UU);                                                \
    float p = 0.f;                                                         \
    _Pragma("unroll")                                                      \
    for (int s = 0; s < 16; ++s) {                                         \
      float dA = __builtin_amdgcn_exp2f((DT) * A2[s]);                     \
      h[s] = fmaf(dA, h[s], du * BF[s]);                                   \
      p = fmaf(h[s], CF[s], p);                                            \
    }                                                                      \
    p = dpp_add<0xB1>(p);                                                  \
    p = dpp_add<0x4E>(p);                                                  \
    if (sg2 == 0) xsb[idx] = (bf16)(fmaf((UU), dskip, p) * (GV));          \
  }

  for (int t = 0; t < CL; t += 2) {
    // prefetch step t+1 into buf1
    dt1 = (float)dtb[idx + DIN]; g1 = (float)gb[idx + DIN]; u1 = (float)xsb[idx + DIN];
    LOAD16(B1, bp + 128) LOAD16(C1, bp + 192)
    LSTEP(dt0, g0, u0, B0, C0)
    idx += DIN; bp += 128;
    // prefetch step t+2 into buf0
    dt0 = (float)dtb[idx + DIN]; g0 = (float)gb[idx + DIN]; u0 = (float)xsb[idx + DIN];
    LOAD16(B0, bp + 128) LOAD16(C0, bp + 192)
    LSTEP(dt1, g1, u1, B1, C1)
    idx += DIN; bp += 128;
  }
#undef LSTEP

  if (chunk < NC - 1) {
    bf16* hp = hf + (((size_t)chunk * NCH + ch) << 6) + sg2 * 16;
    bf16x8 p0, p1;
#pragma unroll
    for (int j = 0; j < 8; j++) { p0.v[j] = (bf16)h[j]; p1.v[j] = (bf16)h[8 + j]; }
    *(bf16x8*)hp       = p0;
    *(bf16x8*)(hp + 8) = p1;
    if (sg2 == 0) Ssum[chunk * NCH + ch] = S;
  }
}

// ---------------- chunked selective scan, pass 2: boundary fixup ----------------
// y_l += (C_l . G_l)*g_l with G_l = (prod dA up to l) * H_enter. Ping-pong
// prefetch of dt/C/y/g (same depth-1 pipeline as pass 1).
__launch_bounds__(256)
__global__ void scan_fix_k(const bf16* __restrict__ dtb, bf16* __restrict__ xsb,
                           const bf16* __restrict__ gb, const float* __restrict__ dblf,
                           const float* __restrict__ A_log,
                           const bf16* __restrict__ hf, const float* __restrict__ Ssum) {
  int gt = blockIdx.x * 256 + threadIdx.x;
  int sg2  = gt & 3;
  int rest = gt >> 2;
  int ch = rest % NCH;
  int cf = 1 + rest / NCH;      // chunk 1..3
  int d  = ch % DIN;
  int eb = ch / DIN;
  int e  = eb >> 2;

  const float LOG2E = 1.44269504088896f;
  float A2[16];
  const float4* Ap = (const float4*)(A_log + ((size_t)e * DIN + d) * DSN + sg2 * 16);
#pragma unroll
  for (int i = 0; i < 4; i++) {
    float4 a = Ap[i];
    A2[4 * i + 0] = -__expf(a.x) * LOG2E;
    A2[4 * i + 1] = -__expf(a.y) * LOG2E;
    A2[4 * i + 2] = -__expf(a.z) * LOG2E;
    A2[4 * i + 3] = -__expf(a.w) * LOG2E;
  }

  // entering state G = H_cf (Horner combine of stored chunk finals)
  float G[16];
  {
    const bf16* hp = hf + ((size_t)ch << 6) + sg2 * 16;   // chunk 0
#pragma unroll
    for (int s = 0; s < 16; ++s) G[s] = (float)hp[s];
  }
  for (int j = 1; j < cf; ++j) {
    float Sj = Ssum[j * NCH + ch];
    const bf16* hp = hf + (((size_t)j * NCH + ch) << 6) + sg2 * 16;
#pragma unroll
    for (int s = 0; s < 16; ++s)
      G[s] = fmaf(__builtin_amdgcn_exp2f(A2[s] * Sj), G[s], (float)hp[s]);
  }

  int l0 = cf * CL;
  unsigned idx = (unsigned)eb * (LL * DIN) + (unsigned)(l0 * DIN) + (unsigned)d;
  const float* bp = dblf + ((size_t)eb * LL + l0) * 128 + sg2 * 16;

  float dt0, y0, g0, dt1, y1, g1;
  float C0[16], C1[16];
  dt0 = (float)dtb[idx]; y0 = (float)xsb[idx]; g0 = (float)gb[idx];
  LOAD16(C0, bp + 64)

#define FSTEP(DT, YV, GV, CF)                                              \
  {                                                                        \
    float p = 0.f;                                                         \
    _Pragma("unroll")                                                      \
    for (int s = 0; s < 16; ++s) {                                         \
      G[s] *= __builtin_amdgcn_exp2f((DT) * A2[s]);                        \
      p = fmaf(G[s], CF[s], p);                                            \
    }                                                                      \
    p = dpp_add<0xB1>(p);                                                  \
    p = dpp_add<0x4E>(p);                                                  \
    if (sg2 == 0) xsb[idx] = (bf16)fmaf(p, (GV), (YV));                    \
  }

  for (int t = 0; t < CL; t += 2) {
    dt1 = (float)dtb[idx + DIN]; y1 = (float)xsb[idx + DIN]; g1 = (float)gb[idx + DIN];
    LOAD16(C1, bp + 192)
    FSTEP(dt0, y0, g0, C0)
    idx += DIN; bp += 128;
    dt0 = (float)dtb[idx + DIN]; y0 = (float)xsb[idx + DIN]; g0 = (float)gb[idx + DIN];
    LOAD16(C0, bp + 192)
    FSTEP(dt1, y1, g1, C1)
    idx += DIN; bp += 128;
  }
#undef FSTEP
}

extern "C" void kernel_launch(void* const* d_in, const int* in_sizes, int n_in,
                              void* d_out, int out_size, void* d_ws, size_t ws_size,
                              hipStream_t stream) {
  const float* base   = (const float*)d_in[0];
  const float* per_ch = (const float*)d_in[1];
  const float* alpha  = (const float*)d_in[2];
  const float* ln_g   = (const float*)d_in[3];
  const float* ln_b   = (const float*)d_in[4];
  const float* W_in   = (const float*)d_in[5];
  const float* conv_w = (const float*)d_in[6];
  const float* conv_b = (const float*)d_in[7];
  const float* W_x    = (const float*)d_in[8];
  const float* W_dt   = (const float*)d_in[9];
  const float* b_dt   = (const float*)d_in[10];
  const float* A_log  = (const float*)d_in[11];
  const float* D_skip = (const float*)d_in[12];
  const float* W_out  = (const float*)d_in[13];
  float* out = (float*)d_out;
  (void)in_sizes; (void)n_in; (void)out_size; (void)ws_size;

  // Workspace layout (131.9 MB), lifetime overlays:
  //  R1 [37.75M]: Abf (18.87M) -> xs (row-major) -> y (scan writes in-place)
  //  R2 [37.75M]: g = silu(z)
  //  R3 [37.75M]: xp -> dt (row-major [M][DIN])
  //  R4 [14.16M]: W_inT -> [WoutT 7.08M | dblf 6.29M | Ssum 221KB in spare]
  //  R5 [ 2.36M]: W_xT ;  R6 [0.59M]: W_dtT ;  R7 [1.57M]: dblp bf16 (ld 64)
  //  hf (chunk finals, bf16 [3][NCH][64] = 7.08M) lives in d_out before copy4.
  char* ws = (char*)d_ws;
  const size_t R = (size_t)EXP * MM * DIN * 2;            // 37,748,736
  bf16* Abf   = (bf16*)ws;
  bf16* xsws  = (bf16*)ws;
  bf16* gws   = (bf16*)(ws + R);
  bf16* dtws  = (bf16*)(ws + 2 * R);
  char* R4    = ws + 3 * R;
  bf16*  WinT  = (bf16*)R4;
  bf16*  WoutT = (bf16*)R4;                               // overlays WinT after MODE0
  float* dblf  = (float*)(R4 + 7077888);                  // E*M*128 f32 = 6.29M
  float* Ssum  = (float*)(R4 + 13369344);                 // 3*NCH f32 = 221KB (R4 spare)
  bf16* WxT   = (bf16*)(ws + 3 * R + 14155776);
  bf16* WdtT  = (bf16*)(ws + 3 * R + 14155776 + 2359296);
  bf16* dblp  = (bf16*)(ws + 3 * R + 14155776 + 2359296 + 589824);
  bf16* hf    = (bf16*)d_out;                             // scratch until copy4

  dim3 blk2(32, 8);

  // prep: LN->bf16, weight transposes (bf16, B^T layout)
  ln_apply_k<<<EXP * BB * LL / 4, 256, 0, stream>>>(per_ch, ln_g, ln_b, Abf);
  tcvt_k<<<dim3(96, 24, EXP), blk2, 0, stream>>>(W_in, WinT, 768, 3072, 768,
        (size_t)768 * 3072, (size_t)3072 * 768, 0, nullptr);
  tcvt_k<<<dim3(8, 48, EXP), blk2, 0, stream>>>(W_x, WxT, 1536, 176, 1536,
        (size_t)1536 * 176, (size_t)256 * 1536, 1, nullptr);
  tcvt_k<<<dim3(48, 2, EXP), blk2, 0, stream>>>(W_dt, WdtT, 48, 1536, 64,
        (size_t)48 * 1536, (size_t)1536 * 64, 0, nullptr);

  // xz = Abf @ W_in -> xp (dtws), silu(z) (gws)
  mfma_gemm_k<0><<<dim3(24, 32, EXP), 256, 0, stream>>>(Abf, WinT, 768, DD,
        (size_t)MM * DD, (size_t)3072 * 768, (size_t)MM * DIN,
        dtws, gws, nullptr, nullptr);

  // W_outT (pre-scaled by softmax(alpha)) -- overlays W_inT, safe after MODE0
  tcvt_k<<<dim3(24, 48, EXP), blk2, 0, stream>>>(W_out, WoutT, 1536, 768, 1536,
        (size_t)1536 * 768, (size_t)768 * 1536, 2, alpha);

  // causal conv + silu -> xs (overlays Abf, safe after MODE0)
  conv_silu_k<<<EXP * BB * LL * DIN / 8 / 256, 256, 0, stream>>>(dtws, conv_w, conv_b, xsws);

  // dbl = xs @ W_x: dt cols -> dblp (bf16, ld 64); B|C -> dblf f32 row-major [M][128]
  mfma_gemm_k<1><<<dim3(2, 32, EXP), 256, 0, stream>>>(xsws, WxT, 1536, DIN,
        (size_t)MM * DIN, (size_t)256 * 1536, (size_t)MM * 64,
        dblp, nullptr, nullptr, dblf);

  // dt = softplus(dblp @ W_dt + b_dt) -> dtws
  mfma_gemm_k<2><<<dim3(12, 32, EXP), 256, 0, stream>>>(dblp, WdtT, 64, 64,
        (size_t)MM * 64, (size_t)1536 * 64, (size_t)MM * DIN,
        dtws, nullptr, b_dt, nullptr);

  // chunked scan: local pass (all 4 chunks in parallel), then boundary fixup
  scan_local_k<<<NCH * 4 * NC / 256, 256, 0, stream>>>(
      dtws, xsws, gws, dblf, A_log, D_skip, hf, Ssum);
  scan_fix_k<<<NCH * 4 * (NC - 1) / 256, 256, 0, stream>>>(
      dtws, xsws, gws, dblf, A_log, hf, Ssum);

  // out = base (after hf scratch is dead); out += sum_e y_e @ (w_e*W_out_e)
  copy4_k<<<MM * DD / 4 / 256, 256, 0, stream>>>(base, out, MM * DD / 4);
  mfma_gemm_k<3><<<dim3(6, 32, EXP), 256, 0, stream>>>(xsws, WoutT, 1536, DIN,
        (size_t)MM * DIN, (size_t)768 * 1536, 0,
        nullptr, nullptr, nullptr, out);
}

// Round 11
// 1302.006 us; speedup vs baseline: 1.0186x; 1.0166x over previous
//
#include <hip/hip_runtime.h>
#include <hip/hip_bf16.h>

typedef __hip_bfloat16 bf16;
typedef unsigned short u16;
typedef __attribute__((ext_vector_type(8))) short s16x8;
typedef __attribute__((ext_vector_type(4))) short s16x4;
typedef __attribute__((ext_vector_type(4))) float f32x4;

#define EXP 3
#define BB  4
#define LL  1024
#define DD  768
#define DSN 64
#define DIN 1536
#define DTR 48
#define MM  4096       // B*L rows per expert
#define NCH 18432      // EXP*BB*DIN channels
#define NC  4          // L-chunks
#define CL  256        // steps per chunk

struct alignas(8)  bf16x4 { bf16 v[4]; };
struct alignas(16) bf16x8 { bf16 v[8]; };

__device__ __forceinline__ float siluf(float x) { return x / (1.f + __expf(-x)); }
__device__ __forceinline__ float softplusf(float x) { return (x > 15.f) ? x : log1pf(__expf(x)); }
__device__ __forceinline__ float bf2f(u16 h) { union { unsigned u; float f; } x; x.u = ((unsigned)h) << 16; return x.f; }

// DPP add: x + perm(x). quad_perm(1,0,3,2)=0xB1, quad_perm(2,3,0,1)=0x4E ->
// 4-lane allreduce in two steps (quad groups never cross channel boundaries).
template <int CTRL>
__device__ __forceinline__ float dpp_add(float x) {
  int y = __builtin_amdgcn_update_dpp(0, __float_as_int(x), CTRL, 0xf, 0xf, true);
  return x + __int_as_float(y);
}

__device__ __forceinline__ f32x4 vsplat(float s) { f32x4 r; r.x = s; r.y = s; r.z = s; r.w = s; return r; }
__device__ __forceinline__ f32x4 ld4f(const float* p) { return *(const f32x4*)p; }
__device__ __forceinline__ f32x4 exp2v(f32x4 x) {
  f32x4 r;
  r.x = __builtin_amdgcn_exp2f(x.x);
  r.y = __builtin_amdgcn_exp2f(x.y);
  r.z = __builtin_amdgcn_exp2f(x.z);
  r.w = __builtin_amdgcn_exp2f(x.w);
  return r;
}
// A2 = -exp(A_log) * log2(e), elementwise on a loaded f32x4
__device__ __forceinline__ f32x4 mkA2(f32x4 a) {
  const float LOG2E = 1.44269504088896f;
  f32x4 r;
  r.x = -__builtin_amdgcn_exp2f(a.x * LOG2E) * LOG2E;
  r.y = -__builtin_amdgcn_exp2f(a.y * LOG2E) * LOG2E;
  r.z = -__builtin_amdgcn_exp2f(a.z * LOG2E) * LOG2E;
  r.w = -__builtin_amdgcn_exp2f(a.w * LOG2E) * LOG2E;
  return r;
}

// ---------------- LayerNorm apply + bf16 convert: per_ch -> Abf ----------------
__launch_bounds__(256)
__global__ void ln_apply_k(const float* __restrict__ pc, const float* __restrict__ lng,
                           const float* __restrict__ lnb, bf16* __restrict__ out) {
  int row  = blockIdx.x * 4 + (threadIdx.x >> 6);
  int lane = threadIdx.x & 63;
  const float* x = pc + (size_t)row * DD;
  float4 v[3];
  float s = 0.f, sq = 0.f;
#pragma unroll
  for (int i = 0; i < 3; i++) {
    v[i] = *(const float4*)(x + lane * 4 + i * 256);
    s  += v[i].x + v[i].y + v[i].z + v[i].w;
    sq += v[i].x * v[i].x + v[i].y * v[i].y + v[i].z * v[i].z + v[i].w * v[i].w;
  }
#pragma unroll
  for (int o = 1; o < 64; o <<= 1) { s += __shfl_xor(s, o); sq += __shfl_xor(sq, o); }
  float mu = s * (1.f / 768.f);
  float rs = rsqrtf(sq * (1.f / 768.f) - mu * mu + 1e-5f);
  bf16* op = out + (size_t)row * DD;
#pragma unroll
  for (int i = 0; i < 3; i++) {
    int col = lane * 4 + i * 256;
    float4 g4 = *(const float4*)(lng + col);
    float4 b4 = *(const float4*)(lnb + col);
    bf16x4 pk;
    pk.v[0] = (bf16)((v[i].x - mu) * rs * g4.x + b4.x);
    pk.v[1] = (bf16)((v[i].y - mu) * rs * g4.y + b4.y);
    pk.v[2] = (bf16)((v[i].z - mu) * rs * g4.z + b4.z);
    pk.v[3] = (bf16)((v[i].w - mu) * rs * g4.w + b4.w);
    *(bf16x4*)(op + col) = pk;
  }
}

// ---------------- transpose + f32->bf16 weight conversion ----------------
__launch_bounds__(256)
__global__ void tcvt_k(const float* __restrict__ in, bf16* __restrict__ out,
                       int Ksrc, int ldin, int ldout,
                       size_t sIn, size_t sOut, int mode, const float* __restrict__ alphap) {
  __shared__ float tl[32][33];
  int z = blockIdx.z;
  const float* src = in + (size_t)z * sIn;
  bf16* dst = out + (size_t)z * sOut;
  int n0 = blockIdx.x * 32, k0 = blockIdx.y * 32;
  int tx = threadIdx.x, ty = threadIdx.y;
  int n = n0 + tx;
  int c = n; bool nv = true;
  if (mode == 1) {
    if (n < 48)       c = n;
    else if (n < 64)  nv = false;
    else if (n < 192) c = n - 16;
    else              nv = false;
  }
  float scale = 1.f;
  if (mode == 2) {
    float a0 = alphap[0], a1 = alphap[1], a2 = alphap[2];
    float mx = fmaxf(a0, fmaxf(a1, a2));
    float e0 = __expf(a0 - mx), e1 = __expf(a1 - mx), e2 = __expf(a2 - mx);
    scale = ((z == 0) ? e0 : (z == 1) ? e1 : e2) / (e0 + e1 + e2);
  }
#pragma unroll
  for (int i = 0; i < 32; i += 8) {
    int k = k0 + ty + i;
    float v = (nv && k < Ksrc) ? src[(size_t)k * ldin + c] : 0.f;
    tl[ty + i][tx] = v * scale;
  }
  __syncthreads();
#pragma unroll
  for (int i = 0; i < 32; i += 8) {
    dst[(size_t)(n0 + ty + i) * ldout + (k0 + tx)] = (bf16)tl[tx][ty + i];
  }
}

// ---------------- causal depthwise conv (K=4) + SiLU, 8 channels/thread ----------------
__launch_bounds__(256)
__global__ void conv_silu_k(const bf16* __restrict__ xp, const float* __restrict__ cw,
                            const float* __restrict__ cb, bf16* __restrict__ xs) {
  long i = ((long)blockIdx.x * 256 + threadIdx.x) * 8;   // elem index, 8 channels
  int  c  = (int)(i % DIN);
  long rl = i / DIN;                                     // (e*B + b)*L + l
  int  l  = (int)(rl & (LL - 1));
  int  e  = (int)(rl >> 12);                             // B*L = 4096
  const float* wp  = cw + (size_t)e * DIN * 4 + (size_t)c * 4;
  const float* cbp = cb + (size_t)e * DIN + c;
  float acc[8];
#pragma unroll
  for (int j = 0; j < 8; j++) acc[j] = cbp[j];
#pragma unroll
  for (int tap = 0; tap < 4; tap++) {
    if (l - 3 + tap >= 0) {
      s16x8 xv = *(const s16x8*)(const void*)(xp + (rl + tap - 3) * DIN + c);
#pragma unroll
      for (int j = 0; j < 8; j++)
        acc[j] = fmaf(bf2f((u16)xv[j]), wp[j * 4 + tap], acc[j]);
    }
  }
  bf16x8 pk;
#pragma unroll
  for (int j = 0; j < 8; j++) pk.v[j] = (bf16)siluf(acc[j]);
  *(bf16x8*)(xs + rl * DIN + c) = pk;
}

// ---------------- bf16 MFMA GEMM (R5 measured-best reg-staged version) ----------------
// MODE 0: xz GEMM  -> o0=xp bf16 (n<DIN), o1=silu(z) bf16
// MODE 1: dbl GEMM -> gc<64 -> dblp bf16 (ld 64); gc 64..191 -> dblf f32 [M][128]
// MODE 2: dt GEMM  -> o0=softplus(acc + bias[gc]) bf16 (row-major [M][DIN])
// MODE 3: out GEMM -> atomicAdd into outp (W_out pre-scaled by softmax(alpha))
template<int MODE>
__launch_bounds__(256)
__global__ void mfma_gemm_k(const bf16* __restrict__ A, const bf16* __restrict__ Bt,
                            int Kdim, int lda,
                            size_t sA, size_t sB, size_t sO,
                            bf16* __restrict__ o0, bf16* __restrict__ o1,
                            const float* __restrict__ bias,
                            float* __restrict__ outp) {
  __shared__ short As[128 * 32];
  __shared__ short Bs[128 * 32];
  int z = blockIdx.z;
  A  += (size_t)z * sA;
  Bt += (size_t)z * sB;
  if (o0) o0 += (size_t)z * sO;
  if (o1) o1 += (size_t)z * sO;
  if constexpr (MODE == 1) outp += (size_t)z * (size_t)MM * 128;
  const float* bz = (MODE == 2) ? bias + (size_t)z * DIN : bias;

  int t = threadIdx.x;
  int l = t & 63, w = t >> 6;
  int wr = w >> 1, wc = w & 1;
  int n0 = blockIdx.x * 128, r0 = blockIdx.y * 128;

  int row = t >> 2, c3 = t & 3, col = c3 * 8;
  int plo = ((c3 & 1) ? 16 : 0) + ((c3 & 2) ? 4 : 0);   // k-permuted LDS slot
  int lrow = (l & 15) * 32 + (l >> 4) * 8;

  f32x4 acc[4][4] = {};

  for (int k0 = 0; k0 < Kdim; k0 += 32) {
    s16x8 va0 = *(const s16x8*)(const void*)(A  + (size_t)(r0 + row)      * lda  + k0 + col);
    s16x8 va1 = *(const s16x8*)(const void*)(A  + (size_t)(r0 + row + 64) * lda  + k0 + col);
    s16x8 vb0 = *(const s16x8*)(const void*)(Bt + (size_t)(n0 + row)      * Kdim + k0 + col);
    s16x8 vb1 = *(const s16x8*)(const void*)(Bt + (size_t)(n0 + row + 64) * Kdim + k0 + col);
    __syncthreads();   // previous iteration's ds_reads done
    *(s16x4*)(As + row * 32 + plo)          = __builtin_shufflevector(va0, va0, 0, 1, 2, 3);
    *(s16x4*)(As + row * 32 + plo + 8)      = __builtin_shufflevector(va0, va0, 4, 5, 6, 7);
    *(s16x4*)(As + (row + 64) * 32 + plo)     = __builtin_shufflevector(va1, va1, 0, 1, 2, 3);
    *(s16x4*)(As + (row + 64) * 32 + plo + 8) = __builtin_shufflevector(va1, va1, 4, 5, 6, 7);
    *(s16x4*)(Bs + row * 32 + plo)          = __builtin_shufflevector(vb0, vb0, 0, 1, 2, 3);
    *(s16x4*)(Bs + row * 32 + plo + 8)      = __builtin_shufflevector(vb0, vb0, 4, 5, 6, 7);
    *(s16x4*)(Bs + (row + 64) * 32 + plo)     = __builtin_shufflevector(vb1, vb1, 0, 1, 2, 3);
    *(s16x4*)(Bs + (row + 64) * 32 + plo + 8) = __builtin_shufflevector(vb1, vb1, 4, 5, 6, 7);
    __syncthreads();
    s16x8 af[4], bfv[4];
#pragma unroll
    for (int m = 0; m < 4; m++) af[m]  = *(const s16x8*)(As + (wr * 64 + m * 16) * 32 + lrow);
#pragma unroll
    for (int n = 0; n < 4; n++) bfv[n] = *(const s16x8*)(Bs + (wc * 64 + n * 16) * 32 + lrow);
#pragma unroll
    for (int m = 0; m < 4; m++)
#pragma unroll
      for (int n = 0; n < 4; n++)
        acc[m][n] = __builtin_amdgcn_mfma_f32_16x16x32_bf16(af[m], bfv[n], acc[m][n], 0, 0, 0);
  }

  int rb = r0 + wr * 64 + ((l >> 4) << 2);
  int cb = n0 + wc * 64 + (l & 15);
#pragma unroll
  for (int m = 0; m < 4; m++)
#pragma unroll
    for (int n = 0; n < 4; n++)
#pragma unroll
      for (int r = 0; r < 4; r++) {
        int gr = rb + m * 16 + r;
        int gc = cb + n * 16;
        float v = acc[m][n][r];
        if constexpr (MODE == 0) {
          if (n0 < DIN) o0[(size_t)gr * DIN + gc] = (bf16)v;
          else          o1[(size_t)gr * DIN + (gc - DIN)] = (bf16)siluf(v);
        } else if constexpr (MODE == 1) {
          if (gc < 64)       o0[(size_t)gr * 64 + gc] = (bf16)v;
          else if (gc < 192) outp[(size_t)gr * 128 + (gc - 64)] = v;
        } else if constexpr (MODE == 2) {
          o0[(size_t)gr * DIN + gc] = (bf16)softplusf(v + bz[gc]);
        } else {
          atomicAdd(&outp[(size_t)gr * DD + gc], v);
        }
      }
}

// ---------------- out = base (init before atomic accumulation) ----------------
__launch_bounds__(256)
__global__ void copy4_k(const float* __restrict__ s, float* __restrict__ d, int n4) {
  int i = blockIdx.x * 256 + threadIdx.x;
  if (i < n4) ((float4*)d)[i] = ((const float4*)s)[i];
}

// ---------------- chunked selective scan, pass 1: local scans ----------------
// 4 lanes/channel x 16 states/lane x 4 L-chunks. ALL state in NAMED f32x4
// vector registers (R9/R10's float[16] arrays + float4* punning defeated
// SROA -> scratch spills, VGPR=64 with a 96+ float live set, 30% VALUBusy).
// Depth-1 full prefetch (dt/g/u/B/C) via 2-step ping-pong; launch_bounds
// (256,4) allows the ~120-VGPR live set at 4 waves/SIMD.
__launch_bounds__(256, 4)
__global__ void scan_local_k(const bf16* __restrict__ dtb, bf16* __restrict__ xsb,
                             const bf16* __restrict__ gb, const float* __restrict__ dblf,
                             const float* __restrict__ A_log, const float* __restrict__ Dsk,
                             bf16* __restrict__ hf, float* __restrict__ Ssum) {
  int gt = blockIdx.x * 256 + threadIdx.x;
  int sg2  = gt & 3;            // states [sg2*16, sg2*16+16)
  int rest = gt >> 2;
  int ch    = rest % NCH;       // eb*DIN + d
  int chunk = rest / NCH;
  int d  = ch % DIN;
  int eb = ch / DIN;
  int e  = eb >> 2;             // B == 4

  const float* Ab = A_log + ((size_t)e * DIN + d) * DSN + sg2 * 16;
  f32x4 A2a = mkA2(ld4f(Ab));
  f32x4 A2b = mkA2(ld4f(Ab + 4));
  f32x4 A2c = mkA2(ld4f(Ab + 8));
  f32x4 A2d = mkA2(ld4f(Ab + 12));
  f32x4 ha = {}, hb = {}, hc = {}, hd = {};
  float dskip = Dsk[(size_t)e * DIN + d];

  int l0 = chunk * CL;
  unsigned idx = (unsigned)eb * (LL * DIN) + (unsigned)(l0 * DIN) + (unsigned)d;
  const float* bp = dblf + ((size_t)eb * LL + l0) * 128 + sg2 * 16;

  float S = 0.f;
  float dt0 = (float)dtb[idx], g0 = (float)gb[idx], u0 = (float)xsb[idx];
  f32x4 Ba = ld4f(bp),      Bb = ld4f(bp + 4),  Bc = ld4f(bp + 8),  Bd = ld4f(bp + 12);
  f32x4 Ca = ld4f(bp + 64), Cb = ld4f(bp + 68), Cc = ld4f(bp + 72), Cd = ld4f(bp + 76);

#define LSTEP(DT, GV, UU, B0_, B1_, B2_, B3_, C0_, C1_, C2_, C3_)            \
  {                                                                          \
    S += (DT);                                                               \
    f32x4 dtv = vsplat(DT);                                                  \
    f32x4 duv = vsplat((DT) * (UU));                                         \
    f32x4 dA = exp2v(dtv * A2a); ha = dA * ha + duv * (B0_);                 \
    f32x4 ps = ha * (C0_);                                                   \
    dA = exp2v(dtv * A2b); hb = dA * hb + duv * (B1_); ps += hb * (C1_);     \
    dA = exp2v(dtv * A2c); hc = dA * hc + duv * (B2_); ps += hc * (C2_);     \
    dA = exp2v(dtv * A2d); hd = dA * hd + duv * (B3_); ps += hd * (C3_);     \
    float p = (ps.x + ps.y) + (ps.z + ps.w);                                 \
    p = dpp_add<0xB1>(p);                                                    \
    p = dpp_add<0x4E>(p);                                                    \
    if (sg2 == 0) xsb[idx] = (bf16)(fmaf((UU), dskip, p) * (GV));            \
  }

  for (int t = 0; t < CL; t += 2) {
    // prefetch step t+1 into N/M
    float dt1 = (float)dtb[idx + DIN], g1 = (float)gb[idx + DIN], u1 = (float)xsb[idx + DIN];
    f32x4 Na = ld4f(bp + 128), Nb = ld4f(bp + 132), Nc = ld4f(bp + 136), Nd = ld4f(bp + 140);
    f32x4 Ma = ld4f(bp + 192), Mb = ld4f(bp + 196), Mc = ld4f(bp + 200), Md = ld4f(bp + 204);
    LSTEP(dt0, g0, u0, Ba, Bb, Bc, Bd, Ca, Cb, Cc, Cd)
    idx += DIN; bp += 128;
    // prefetch step t+2 into B/C
    dt0 = (float)dtb[idx + DIN]; g0 = (float)gb[idx + DIN]; u0 = (float)xsb[idx + DIN];
    Ba = ld4f(bp + 128); Bb = ld4f(bp + 132); Bc = ld4f(bp + 136); Bd = ld4f(bp + 140);
    Ca = ld4f(bp + 192); Cb = ld4f(bp + 196); Cc = ld4f(bp + 200); Cd = ld4f(bp + 204);
    LSTEP(dt1, g1, u1, Na, Nb, Nc, Nd, Ma, Mb, Mc, Md)
    idx += DIN; bp += 128;
  }
#undef LSTEP

  if (chunk < NC - 1) {
    bf16* hp = hf + (((size_t)chunk * NCH + ch) << 6) + sg2 * 16;
    bf16x8 p0, p1;
    p0.v[0] = (bf16)ha.x; p0.v[1] = (bf16)ha.y; p0.v[2] = (bf16)ha.z; p0.v[3] = (bf16)ha.w;
    p0.v[4] = (bf16)hb.x; p0.v[5] = (bf16)hb.y; p0.v[6] = (bf16)hb.z; p0.v[7] = (bf16)hb.w;
    p1.v[0] = (bf16)hc.x; p1.v[1] = (bf16)hc.y; p1.v[2] = (bf16)hc.z; p1.v[3] = (bf16)hc.w;
    p1.v[4] = (bf16)hd.x; p1.v[5] = (bf16)hd.y; p1.v[6] = (bf16)hd.z; p1.v[7] = (bf16)hd.w;
    *(bf16x8*)hp       = p0;
    *(bf16x8*)(hp + 8) = p1;
    if (sg2 == 0) Ssum[chunk * NCH + ch] = S;
  }
}

// ---------------- chunked selective scan, pass 2: boundary fixup ----------------
// y_l += (C_l . G_l)*g_l with G_l = (prod dA up to l) * H_enter. Named-vector
// registers; ping-pong prefetch of dt/y/g/C.
__launch_bounds__(256, 4)
__global__ void scan_fix_k(const bf16* __restrict__ dtb, bf16* __restrict__ xsb,
                           const bf16* __restrict__ gb, const float* __restrict__ dblf,
                           const float* __restrict__ A_log,
                           const bf16* __restrict__ hf, const float* __restrict__ Ssum) {
  int gt = blockIdx.x * 256 + threadIdx.x;
  int sg2  = gt & 3;
  int rest = gt >> 2;
  int ch = rest % NCH;
  int cf = 1 + rest / NCH;      // chunk 1..3
  int d  = ch % DIN;
  int eb = ch / DIN;
  int e  = eb >> 2;

  const float* Ab = A_log + ((size_t)e * DIN + d) * DSN + sg2 * 16;
  f32x4 A2a = mkA2(ld4f(Ab));
  f32x4 A2b = mkA2(ld4f(Ab + 4));
  f32x4 A2c = mkA2(ld4f(Ab + 8));
  f32x4 A2d = mkA2(ld4f(Ab + 12));

  // entering state G = H_cf (Horner combine of stored chunk finals)
  f32x4 Ga, Gb, Gc, Gd;
  {
    const bf16* hp = hf + ((size_t)ch << 6) + sg2 * 16;   // chunk 0
    Ga.x = (float)hp[0];  Ga.y = (float)hp[1];  Ga.z = (float)hp[2];  Ga.w = (float)hp[3];
    Gb.x = (float)hp[4];  Gb.y = (float)hp[5];  Gb.z = (float)hp[6];  Gb.w = (float)hp[7];
    Gc.x = (float)hp[8];  Gc.y = (float)hp[9];  Gc.z = (float)hp[10]; Gc.w = (float)hp[11];
    Gd.x = (float)hp[12]; Gd.y = (float)hp[13]; Gd.z = (float)hp[14]; Gd.w = (float)hp[15];
  }
  for (int j = 1; j < cf; ++j) {
    float Sj = Ssum[j * NCH + ch];
    f32x4 Sv = vsplat(Sj);
    const bf16* hp = hf + (((size_t)j * NCH + ch) << 6) + sg2 * 16;
    f32x4 Ha, Hb, Hc, Hd;
    Ha.x = (float)hp[0];  Ha.y = (float)hp[1];  Ha.z = (float)hp[2];  Ha.w = (float)hp[3];
    Hb.x = (float)hp[4];  Hb.y = (float)hp[5];  Hb.z = (float)hp[6];  Hb.w = (float)hp[7];
    Hc.x = (float)hp[8];  Hc.y = (float)hp[9];  Hc.z = (float)hp[10]; Hc.w = (float)hp[11];
    Hd.x = (float)hp[12]; Hd.y = (float)hp[13]; Hd.z = (float)hp[14]; Hd.w = (float)hp[15];
    Ga = exp2v(Sv * A2a) * Ga + Ha;
    Gb = exp2v(Sv * A2b) * Gb + Hb;
    Gc = exp2v(Sv * A2c) * Gc + Hc;
    Gd = exp2v(Sv * A2d) * Gd + Hd;
  }

  int l0 = cf * CL;
  unsigned idx = (unsigned)eb * (LL * DIN) + (unsigned)(l0 * DIN) + (unsigned)d;
  const float* bp = dblf + ((size_t)eb * LL + l0) * 128 + sg2 * 16;

  float dt0 = (float)dtb[idx], y0 = (float)xsb[idx], g0 = (float)gb[idx];
  f32x4 Ca = ld4f(bp + 64), Cb = ld4f(bp + 68), Cc = ld4f(bp + 72), Cd = ld4f(bp + 76);

#define FSTEP(DT, YV, GV, C0_, C1_, C2_, C3_)                                \
  {                                                                          \
    f32x4 dtv = vsplat(DT);                                                  \
    Ga = exp2v(dtv * A2a) * Ga;                                              \
    f32x4 ps = Ga * (C0_);                                                   \
    Gb = exp2v(dtv * A2b) * Gb; ps += Gb * (C1_);                            \
    Gc = exp2v(dtv * A2c) * Gc; ps += Gc * (C2_);                            \
    Gd = exp2v(dtv * A2d) * Gd; ps += Gd * (C3_);                            \
    float p = (ps.x + ps.y) + (ps.z + ps.w);                                 \
    p = dpp_add<0xB1>(p);                                                    \
    p = dpp_add<0x4E>(p);                                                    \
    if (sg2 == 0) xsb[idx] = (bf16)fmaf(p, (GV), (YV));                      \
  }

  for (int t = 0; t < CL; t += 2) {
    float dt1 = (float)dtb[idx + DIN], y1 = (float)xsb[idx + DIN], g1 = (float)gb[idx + DIN];
    f32x4 Na = ld4f(bp + 192), Nb = ld4f(bp + 196), Nc = ld4f(bp + 200), Nd = ld4f(bp + 204);
    FSTEP(dt0, y0, g0, Ca, Cb, Cc, Cd)
    idx += DIN; bp += 128;
    dt0 = (float)dtb[idx + DIN]; y0 = (float)xsb[idx + DIN]; g0 = (float)gb[idx + DIN];
    Ca = ld4f(bp + 192); Cb = ld4f(bp + 196); Cc = ld4f(bp + 200); Cd = ld4f(bp + 204);
    FSTEP(dt1, y1, g1, Na, Nb, Nc, Nd)
    idx += DIN; bp += 128;
  }
#undef FSTEP
}

extern "C" void kernel_launch(void* const* d_in, const int* in_sizes, int n_in,
                              void* d_out, int out_size, void* d_ws, size_t ws_size,
                              hipStream_t stream) {
  const float* base   = (const float*)d_in[0];
  const float* per_ch = (const float*)d_in[1];
  const float* alpha  = (const float*)d_in[2];
  const float* ln_g   = (const float*)d_in[3];
  const float* ln_b   = (const float*)d_in[4];
  const float* W_in   = (const float*)d_in[5];
  const float* conv_w = (const float*)d_in[6];
  const float* conv_b = (const float*)d_in[7];
  const float* W_x    = (const float*)d_in[8];
  const float* W_dt   = (const float*)d_in[9];
  const float* b_dt   = (const float*)d_in[10];
  const float* A_log  = (const float*)d_in[11];
  const float* D_skip = (const float*)d_in[12];
  const float* W_out  = (const float*)d_in[13];
  float* out = (float*)d_out;
  (void)in_sizes; (void)n_in; (void)out_size; (void)ws_size;

  // Workspace layout (131.9 MB), lifetime overlays:
  //  R1 [37.75M]: Abf (18.87M) -> xs (row-major) -> y (scan writes in-place)
  //  R2 [37.75M]: g = silu(z)
  //  R3 [37.75M]: xp -> dt (row-major [M][DIN])
  //  R4 [14.16M]: W_inT -> [WoutT 7.08M | dblf 6.29M | Ssum 221KB in spare]
  //  R5 [ 2.36M]: W_xT ;  R6 [0.59M]: W_dtT ;  R7 [1.57M]: dblp bf16 (ld 64)
  //  hf (chunk finals, bf16 [3][NCH][64] = 7.08M) lives in d_out before copy4.
  char* ws = (char*)d_ws;
  const size_t R = (size_t)EXP * MM * DIN * 2;            // 37,748,736
  bf16* Abf   = (bf16*)ws;
  bf16* xsws  = (bf16*)ws;
  bf16* gws   = (bf16*)(ws + R);
  bf16* dtws  = (bf16*)(ws + 2 * R);
  char* R4    = ws + 3 * R;
  bf16*  WinT  = (bf16*)R4;
  bf16*  WoutT = (bf16*)R4;                               // overlays WinT after MODE0
  float* dblf  = (float*)(R4 + 7077888);                  // E*M*128 f32 = 6.29M
  float* Ssum  = (float*)(R4 + 13369344);                 // 3*NCH f32 = 221KB (R4 spare)
  bf16* WxT   = (bf16*)(ws + 3 * R + 14155776);
  bf16* WdtT  = (bf16*)(ws + 3 * R + 14155776 + 2359296);
  bf16* dblp  = (bf16*)(ws + 3 * R + 14155776 + 2359296 + 589824);
  bf16* hf    = (bf16*)d_out;                             // scratch until copy4

  dim3 blk2(32, 8);

  // prep: LN->bf16, weight transposes (bf16, B^T layout)
  ln_apply_k<<<EXP * BB * LL / 4, 256, 0, stream>>>(per_ch, ln_g, ln_b, Abf);
  tcvt_k<<<dim3(96, 24, EXP), blk2, 0, stream>>>(W_in, WinT, 768, 3072, 768,
        (size_t)768 * 3072, (size_t)3072 * 768, 0, nullptr);
  tcvt_k<<<dim3(8, 48, EXP), blk2, 0, stream>>>(W_x, WxT, 1536, 176, 1536,
        (size_t)1536 * 176, (size_t)256 * 1536, 1, nullptr);
  tcvt_k<<<dim3(48, 2, EXP), blk2, 0, stream>>>(W_dt, WdtT, 48, 1536, 64,
        (size_t)48 * 1536, (size_t)1536 * 64, 0, nullptr);

  // xz = Abf @ W_in -> xp (dtws), silu(z) (gws)
  mfma_gemm_k<0><<<dim3(24, 32, EXP), 256, 0, stream>>>(Abf, WinT, 768, DD,
        (size_t)MM * DD, (size_t)3072 * 768, (size_t)MM * DIN,
        dtws, gws, nullptr, nullptr);

  // W_outT (pre-scaled by softmax(alpha)) -- overlays W_inT, safe after MODE0
  tcvt_k<<<dim3(24, 48, EXP), blk2, 0, stream>>>(W_out, WoutT, 1536, 768, 1536,
        (size_t)1536 * 768, (size_t)768 * 1536, 2, alpha);

  // causal conv + silu -> xs (overlays Abf, safe after MODE0)
  conv_silu_k<<<EXP * BB * LL * DIN / 8 / 256, 256, 0, stream>>>(dtws, conv_w, conv_b, xsws);

  // dbl = xs @ W_x: dt cols -> dblp (bf16, ld 64); B|C -> dblf f32 row-major [M][128]
  mfma_gemm_k<1><<<dim3(2, 32, EXP), 256, 0, stream>>>(xsws, WxT, 1536, DIN,
        (size_t)MM * DIN, (size_t)256 * 1536, (size_t)MM * 64,
        dblp, nullptr, nullptr, dblf);

  // dt = softplus(dblp @ W_dt + b_dt) -> dtws
  mfma_gemm_k<2><<<dim3(12, 32, EXP), 256, 0, stream>>>(dblp, WdtT, 64, 64,
        (size_t)MM * 64, (size_t)1536 * 64, (size_t)MM * DIN,
        dtws, nullptr, b_dt, nullptr);

  // chunked scan: local pass (all 4 chunks in parallel), then boundary fixup
  scan_local_k<<<NCH * 4 * NC / 256, 256, 0, stream>>>(
      dtws, xsws, gws, dblf, A_log, D_skip, hf, Ssum);
  scan_fix_k<<<NCH * 4 * (NC - 1) / 256, 256, 0, stream>>>(
      dtws, xsws, gws, dblf, A_log, hf, Ssum);

  // out = base (after hf scratch is dead); out += sum_e y_e @ (w_e*W_out_e)
  copy4_k<<<MM * DD / 4 / 256, 256, 0, stream>>>(base, out, MM * DD / 4);
  mfma_gemm_k<3><<<dim3(6, 32, EXP), 256, 0, stream>>>(xsws, WoutT, 1536, DIN,
        (size_t)MM * DIN, (size_t)768 * 1536, 0,
        nullptr, nullptr, nullptr, out);
}

// Round 12
// 898.324 us; speedup vs baseline: 1.4763x; 1.4494x over previous
//
#include <hip/hip_runtime.h>
#include <hip/hip_bf16.h>

typedef __hip_bfloat16 bf16;
typedef unsigned short u16;
typedef __attribute__((ext_vector_type(8))) short s16x8;
typedef __attribute__((ext_vector_type(4))) short s16x4;
typedef __attribute__((ext_vector_type(4))) float f32x4;

#define EXP 3
#define BB  4
#define LL  1024
#define DD  768
#define DSN 64
#define DIN 1536
#define DTR 48
#define MM  4096       // B*L rows per expert

struct alignas(8)  bf16x4 { bf16 v[4]; };
struct alignas(16) bf16x8 { bf16 v[8]; };

__device__ __forceinline__ float siluf(float x) { return x / (1.f + __expf(-x)); }
__device__ __forceinline__ float softplusf(float x) { return (x > 15.f) ? x : log1pf(__expf(x)); }
__device__ __forceinline__ float bf2f(u16 h) { union { unsigned u; float f; } x; x.u = ((unsigned)h) << 16; return x.f; }

// DPP row-rotate add; rotate-allreduce {8,4,2,1} -> full 16-lane sum in every lane.
template <int CTRL>
__device__ __forceinline__ float ror_add(float x) {
  int y = __builtin_amdgcn_update_dpp(0, __float_as_int(x), CTRL, 0xf, 0xf, true);
  return x + __int_as_float(y);
}

// ---------------- LayerNorm apply + bf16 convert: per_ch -> Abf ----------------
__launch_bounds__(256)
__global__ void ln_apply_k(const float* __restrict__ pc, const float* __restrict__ lng,
                           const float* __restrict__ lnb, bf16* __restrict__ out) {
  int row  = blockIdx.x * 4 + (threadIdx.x >> 6);
  int lane = threadIdx.x & 63;
  const float* x = pc + (size_t)row * DD;
  float4 v[3];
  float s = 0.f, sq = 0.f;
#pragma unroll
  for (int i = 0; i < 3; i++) {
    v[i] = *(const float4*)(x + lane * 4 + i * 256);
    s  += v[i].x + v[i].y + v[i].z + v[i].w;
    sq += v[i].x * v[i].x + v[i].y * v[i].y + v[i].z * v[i].z + v[i].w * v[i].w;
  }
#pragma unroll
  for (int o = 1; o < 64; o <<= 1) { s += __shfl_xor(s, o); sq += __shfl_xor(sq, o); }
  float mu = s * (1.f / 768.f);
  float rs = rsqrtf(sq * (1.f / 768.f) - mu * mu + 1e-5f);
  bf16* op = out + (size_t)row * DD;
#pragma unroll
  for (int i = 0; i < 3; i++) {
    int col = lane * 4 + i * 256;
    float4 g4 = *(const float4*)(lng + col);
    float4 b4 = *(const float4*)(lnb + col);
    bf16x4 pk;
    pk.v[0] = (bf16)((v[i].x - mu) * rs * g4.x + b4.x);
    pk.v[1] = (bf16)((v[i].y - mu) * rs * g4.y + b4.y);
    pk.v[2] = (bf16)((v[i].z - mu) * rs * g4.z + b4.z);
    pk.v[3] = (bf16)((v[i].w - mu) * rs * g4.w + b4.w);
    *(bf16x4*)(op + col) = pk;
  }
}

// ---------------- transpose + f32->bf16 weight conversion ----------------
__launch_bounds__(256)
__global__ void tcvt_k(const float* __restrict__ in, bf16* __restrict__ out,
                       int Ksrc, int ldin, int ldout,
                       size_t sIn, size_t sOut, int mode, const float* __restrict__ alphap) {
  __shared__ float tl[32][33];
  int z = blockIdx.z;
  const float* src = in + (size_t)z * sIn;
  bf16* dst = out + (size_t)z * sOut;
  int n0 = blockIdx.x * 32, k0 = blockIdx.y * 32;
  int tx = threadIdx.x, ty = threadIdx.y;
  int n = n0 + tx;
  int c = n; bool nv = true;
  if (mode == 1) {
    if (n < 48)       c = n;
    else if (n < 64)  nv = false;
    else if (n < 192) c = n - 16;
    else              nv = false;
  }
  float scale = 1.f;
  if (mode == 2) {
    float a0 = alphap[0], a1 = alphap[1], a2 = alphap[2];
    float mx = fmaxf(a0, fmaxf(a1, a2));
    float e0 = __expf(a0 - mx), e1 = __expf(a1 - mx), e2 = __expf(a2 - mx);
    scale = ((z == 0) ? e0 : (z == 1) ? e1 : e2) / (e0 + e1 + e2);
  }
#pragma unroll
  for (int i = 0; i < 32; i += 8) {
    int k = k0 + ty + i;
    float v = (nv && k < Ksrc) ? src[(size_t)k * ldin + c] : 0.f;
    tl[ty + i][tx] = v * scale;
  }
  __syncthreads();
#pragma unroll
  for (int i = 0; i < 32; i += 8) {
    dst[(size_t)(n0 + ty + i) * ldout + (k0 + tx)] = (bf16)tl[tx][ty + i];
  }
}

// ---------------- causal depthwise conv (K=4) + SiLU, 8 channels/thread ----------------
__launch_bounds__(256)
__global__ void conv_silu_k(const bf16* __restrict__ xp, const float* __restrict__ cw,
                            const float* __restrict__ cb, bf16* __restrict__ xs) {
  long i = ((long)blockIdx.x * 256 + threadIdx.x) * 8;   // elem index, 8 channels
  int  c  = (int)(i % DIN);
  long rl = i / DIN;                                     // (e*B + b)*L + l
  int  l  = (int)(rl & (LL - 1));
  int  e  = (int)(rl >> 12);                             // B*L = 4096
  const float* wp  = cw + (size_t)e * DIN * 4 + (size_t)c * 4;
  const float* cbp = cb + (size_t)e * DIN + c;
  float acc[8];
#pragma unroll
  for (int j = 0; j < 8; j++) acc[j] = cbp[j];
#pragma unroll
  for (int tap = 0; tap < 4; tap++) {
    if (l - 3 + tap >= 0) {
      s16x8 xv = *(const s16x8*)(const void*)(xp + (rl + tap - 3) * DIN + c);
#pragma unroll
      for (int j = 0; j < 8; j++)
        acc[j] = fmaf(bf2f((u16)xv[j]), wp[j * 4 + tap], acc[j]);
    }
  }
  bf16x8 pk;
#pragma unroll
  for (int j = 0; j < 8; j++) pk.v[j] = (bf16)siluf(acc[j]);
  *(bf16x8*)(xs + rl * DIN + c) = pk;
}

// ---------------- bf16 MFMA GEMM, 128x128 tile, BK=32, 4 waves x (64x64) ----------------
// MODE 0: xz GEMM  -> o0=xp bf16 (n<DIN), o1=silu(z) bf16
// MODE 1: dbl GEMM -> gc<64 -> dblp bf16 (ld 64); gc 64..191 -> dblf f32 row-major [M][128]
// MODE 2: dt GEMM  -> o0=softplus(acc + bias[gc]) bf16 (row-major [M][DIN])
// MODE 3: out GEMM -> atomicAdd into outp (W_out pre-scaled by softmax(alpha))
template<int MODE>
__launch_bounds__(256)
__global__ void mfma_gemm_k(const bf16* __restrict__ A, const bf16* __restrict__ Bt,
                            int Kdim, int lda,
                            size_t sA, size_t sB, size_t sO,
                            bf16* __restrict__ o0, bf16* __restrict__ o1,
                            const float* __restrict__ bias,
                            float* __restrict__ outp) {
  __shared__ short As[128 * 32];
  __shared__ short Bs[128 * 32];
  int z = blockIdx.z;
  A  += (size_t)z * sA;
  Bt += (size_t)z * sB;
  if (o0) o0 += (size_t)z * sO;
  if (o1) o1 += (size_t)z * sO;
  if constexpr (MODE == 1) outp += (size_t)z * (size_t)MM * 128;
  const float* bz = (MODE == 2) ? bias + (size_t)z * DIN : bias;

  int t = threadIdx.x;
  int l = t & 63, w = t >> 6;
  int wr = w >> 1, wc = w & 1;
  int n0 = blockIdx.x * 128, r0 = blockIdx.y * 128;

  int row = t >> 2, c3 = t & 3, col = c3 * 8;
  int plo = ((c3 & 1) ? 16 : 0) + ((c3 & 2) ? 4 : 0);   // k-permuted LDS slot
  int lrow = (l & 15) * 32 + (l >> 4) * 8;

  f32x4 acc[4][4] = {};

  for (int k0 = 0; k0 < Kdim; k0 += 32) {
    s16x8 va0 = *(const s16x8*)(const void*)(A  + (size_t)(r0 + row)      * lda  + k0 + col);
    s16x8 va1 = *(const s16x8*)(const void*)(A  + (size_t)(r0 + row + 64) * lda  + k0 + col);
    s16x8 vb0 = *(const s16x8*)(const void*)(Bt + (size_t)(n0 + row)      * Kdim + k0 + col);
    s16x8 vb1 = *(const s16x8*)(const void*)(Bt + (size_t)(n0 + row + 64) * Kdim + k0 + col);
    __syncthreads();   // previous iteration's ds_reads done
    *(s16x4*)(As + row * 32 + plo)          = __builtin_shufflevector(va0, va0, 0, 1, 2, 3);
    *(s16x4*)(As + row * 32 + plo + 8)      = __builtin_shufflevector(va0, va0, 4, 5, 6, 7);
    *(s16x4*)(As + (row + 64) * 32 + plo)     = __builtin_shufflevector(va1, va1, 0, 1, 2, 3);
    *(s16x4*)(As + (row + 64) * 32 + plo + 8) = __builtin_shufflevector(va1, va1, 4, 5, 6, 7);
    *(s16x4*)(Bs + row * 32 + plo)          = __builtin_shufflevector(vb0, vb0, 0, 1, 2, 3);
    *(s16x4*)(Bs + row * 32 + plo + 8)      = __builtin_shufflevector(vb0, vb0, 4, 5, 6, 7);
    *(s16x4*)(Bs + (row + 64) * 32 + plo)     = __builtin_shufflevector(vb1, vb1, 0, 1, 2, 3);
    *(s16x4*)(Bs + (row + 64) * 32 + plo + 8) = __builtin_shufflevector(vb1, vb1, 4, 5, 6, 7);
    __syncthreads();
    s16x8 af[4], bfv[4];
#pragma unroll
    for (int m = 0; m < 4; m++) af[m]  = *(const s16x8*)(As + (wr * 64 + m * 16) * 32 + lrow);
#pragma unroll
    for (int n = 0; n < 4; n++) bfv[n] = *(const s16x8*)(Bs + (wc * 64 + n * 16) * 32 + lrow);
#pragma unroll
    for (int m = 0; m < 4; m++)
#pragma unroll
      for (int n = 0; n < 4; n++)
        acc[m][n] = __builtin_amdgcn_mfma_f32_16x16x32_bf16(af[m], bfv[n], acc[m][n], 0, 0, 0);
  }

  int rb = r0 + wr * 64 + ((l >> 4) << 2);
  int cb = n0 + wc * 64 + (l & 15);
#pragma unroll
  for (int m = 0; m < 4; m++)
#pragma unroll
    for (int n = 0; n < 4; n++)
#pragma unroll
      for (int r = 0; r < 4; r++) {
        int gr = rb + m * 16 + r;
        int gc = cb + n * 16;
        float v = acc[m][n][r];
        if constexpr (MODE == 0) {
          if (n0 < DIN) o0[(size_t)gr * DIN + gc] = (bf16)v;
          else          o1[(size_t)gr * DIN + (gc - DIN)] = (bf16)siluf(v);
        } else if constexpr (MODE == 1) {
          if (gc < 64)       o0[(size_t)gr * 64 + gc] = (bf16)v;
          else if (gc < 192) outp[(size_t)gr * 128 + (gc - 64)] = v;
        } else if constexpr (MODE == 2) {
          o0[(size_t)gr * DIN + gc] = (bf16)softplusf(v + bz[gc]);
        } else {
          atomicAdd(&outp[(size_t)gr * DD + gc], v);
        }
      }
}

// ---------------- out = base (init before atomic accumulation) ----------------
__launch_bounds__(256)
__global__ void copy4_k(const float* __restrict__ s, float* __restrict__ d, int n4) {
  int i = blockIdx.x * 256 + threadIdx.x;
  if (i < n4) ((float4*)d)[i] = ((const float4*)s)[i];
}

// ---------------- selective scan: 16 lanes/channel, 4 states/lane ----------------
// Measured-best (488 us, 65% VALUBusy, VGPR 24): f32 B/C row-major, DPP
// rotate-allreduce, raw v_exp_f32, 32-bit offsets, depth-1 full prefetch
// (dt/u/g/B/C) + unroll 4.
__launch_bounds__(256)
__global__ void scan_k(const bf16* __restrict__ dtb, bf16* __restrict__ xsb,
                       const bf16* __restrict__ gb, const float* __restrict__ dbl,
                       const float* __restrict__ A_log, const float* __restrict__ Dsk) {
  int gt = blockIdx.x * 256 + threadIdx.x;
  int sg = gt & 15;             // states [sg*4, sg*4+4)
  int cidx = gt >> 4;           // (e*B + b)*DIN + d
  int d  = cidx % DIN;
  int eb = cidx / DIN;
  int e  = eb >> 2;             // B == 4

  float4 Ar = *(const float4*)(A_log + ((size_t)e * DIN + d) * DSN + sg * 4);
  const float LOG2E = 1.44269504088896f;
  float4 A2;
  A2.x = -__expf(Ar.x) * LOG2E;
  A2.y = -__expf(Ar.y) * LOG2E;
  A2.z = -__expf(Ar.z) * LOG2E;
  A2.w = -__expf(Ar.w) * LOG2E;
  float4 h = {0.f, 0.f, 0.f, 0.f};
  float dskip = Dsk[(size_t)e * DIN + d];

  unsigned idx  = (unsigned)eb * (LL * DIN) + (unsigned)d;   // bf16 elem offset
  unsigned bofs = (unsigned)eb * (LL * 128) + (unsigned)(sg * 4);

  // prefetch l = 0  (final iteration prefetches 1 row past this (e,b) slice;
  // lands in the next ws region, value unused -- safe)
  float dtv = (float)dtb[idx];
  float u   = (float)xsb[idx];
  float gv  = (float)gb[idx];
  float4 Bv = *(const float4*)(dbl + bofs);
  float4 Cv = *(const float4*)(dbl + bofs + 64);

#pragma unroll 4
  for (int l = 0; l < LL; ++l) {
    unsigned idxn = idx + DIN;
    unsigned bofn = bofs + 128;
    float dtn = (float)dtb[idxn];
    float un  = (float)xsb[idxn];
    float gn  = (float)gb[idxn];
    float4 Bn = *(const float4*)(dbl + bofn);
    float4 Cn = *(const float4*)(dbl + bofn + 64);

    float du = dtv * u;
    float4 dA;
    dA.x = __builtin_amdgcn_exp2f(dtv * A2.x);
    dA.y = __builtin_amdgcn_exp2f(dtv * A2.y);
    dA.z = __builtin_amdgcn_exp2f(dtv * A2.z);
    dA.w = __builtin_amdgcn_exp2f(dtv * A2.w);
    h.x = fmaf(dA.x, h.x, du * Bv.x);
    h.y = fmaf(dA.y, h.y, du * Bv.y);
    h.z = fmaf(dA.z, h.z, du * Bv.z);
    h.w = fmaf(dA.w, h.w, du * Bv.w);
    float p = fmaf(h.x, Cv.x, fmaf(h.y, Cv.y, fmaf(h.z, Cv.z, h.w * Cv.w)));
    p = ror_add<0x128>(p);   // row_ror:8
    p = ror_add<0x124>(p);   // row_ror:4
    p = ror_add<0x122>(p);   // row_ror:2
    p = ror_add<0x121>(p);   // row_ror:1
    if (sg == 0) {
      xsb[idx] = (bf16)(fmaf(u, dskip, p) * gv);  // gated y over xs
    }
    idx = idxn; bofs = bofn;
    dtv = dtn; u = un; gv = gn; Bv = Bn; Cv = Cn;
  }
}

extern "C" void kernel_launch(void* const* d_in, const int* in_sizes, int n_in,
                              void* d_out, int out_size, void* d_ws, size_t ws_size,
                              hipStream_t stream) {
  const float* base   = (const float*)d_in[0];
  const float* per_ch = (const float*)d_in[1];
  const float* alpha  = (const float*)d_in[2];
  const float* ln_g   = (const float*)d_in[3];
  const float* ln_b   = (const float*)d_in[4];
  const float* W_in   = (const float*)d_in[5];
  const float* conv_w = (const float*)d_in[6];
  const float* conv_b = (const float*)d_in[7];
  const float* W_x    = (const float*)d_in[8];
  const float* W_dt   = (const float*)d_in[9];
  const float* b_dt   = (const float*)d_in[10];
  const float* A_log  = (const float*)d_in[11];
  const float* D_skip = (const float*)d_in[12];
  const float* W_out  = (const float*)d_in[13];
  float* out = (float*)d_out;
  (void)in_sizes; (void)n_in; (void)out_size; (void)ws_size;

  // Workspace layout (131.9 MB), lifetime overlays:
  //  R1 [37.75M]: Abf (18.87M) -> xs (row-major) -> y (scan writes in-place)
  //  R2 [37.75M]: g = silu(z)
  //  R3 [37.75M]: xp -> dt (row-major [M][DIN])
  //  R4 [14.16M]: W_inT -> [WoutT 7.08M | dblf f32 row-major [E*M][128] 6.29M]
  //  R5 [ 2.36M]: W_xT ;  R6 [0.59M]: W_dtT ;  R7 [1.57M]: dblp bf16 (ld 64)
  char* ws = (char*)d_ws;
  const size_t R = (size_t)EXP * MM * DIN * 2;            // 37,748,736
  bf16* Abf   = (bf16*)ws;
  bf16* xsws  = (bf16*)ws;
  bf16* gws   = (bf16*)(ws + R);
  bf16* dtws  = (bf16*)(ws + 2 * R);
  char* R4    = ws + 3 * R;
  bf16*  WinT  = (bf16*)R4;
  bf16*  WoutT = (bf16*)R4;                               // overlays WinT after MODE0
  float* dblf  = (float*)(R4 + 7077888);                  // E*M*128 f32 = 6.29M
  bf16* WxT   = (bf16*)(ws + 3 * R + 14155776);
  bf16* WdtT  = (bf16*)(ws + 3 * R + 14155776 + 2359296);
  bf16* dblp  = (bf16*)(ws + 3 * R + 14155776 + 2359296 + 589824);

  dim3 blk2(32, 8);

  // prep: LN->bf16, weight transposes (bf16, B^T layout)
  ln_apply_k<<<EXP * BB * LL / 4, 256, 0, stream>>>(per_ch, ln_g, ln_b, Abf);
  tcvt_k<<<dim3(96, 24, EXP), blk2, 0, stream>>>(W_in, WinT, 768, 3072, 768,
        (size_t)768 * 3072, (size_t)3072 * 768, 0, nullptr);
  tcvt_k<<<dim3(8, 48, EXP), blk2, 0, stream>>>(W_x, WxT, 1536, 176, 1536,
        (size_t)1536 * 176, (size_t)256 * 1536, 1, nullptr);
  tcvt_k<<<dim3(48, 2, EXP), blk2, 0, stream>>>(W_dt, WdtT, 48, 1536, 64,
        (size_t)48 * 1536, (size_t)1536 * 64, 0, nullptr);

  // xz = Abf @ W_in -> xp (dtws), silu(z) (gws)
  mfma_gemm_k<0><<<dim3(24, 32, EXP), 256, 0, stream>>>(Abf, WinT, 768, DD,
        (size_t)MM * DD, (size_t)3072 * 768, (size_t)MM * DIN,
        dtws, gws, nullptr, nullptr);

  // W_outT (pre-scaled by softmax(alpha)) -- overlays W_inT, safe after MODE0
  tcvt_k<<<dim3(24, 48, EXP), blk2, 0, stream>>>(W_out, WoutT, 1536, 768, 1536,
        (size_t)1536 * 768, (size_t)768 * 1536, 2, alpha);

  // causal conv + silu -> xs (overlays Abf, safe after MODE0)
  conv_silu_k<<<EXP * BB * LL * DIN / 8 / 256, 256, 0, stream>>>(dtws, conv_w, conv_b, xsws);

  // dbl = xs @ W_x: dt cols -> dblp (bf16, ld 64); B|C -> dblf f32 row-major [M][128]
  mfma_gemm_k<1><<<dim3(2, 32, EXP), 256, 0, stream>>>(xsws, WxT, 1536, DIN,
        (size_t)MM * DIN, (size_t)256 * 1536, (size_t)MM * 64,
        dblp, nullptr, nullptr, dblf);

  // dt = softplus(dblp @ W_dt + b_dt) -> dtws
  mfma_gemm_k<2><<<dim3(12, 32, EXP), 256, 0, stream>>>(dblp, WdtT, 64, 64,
        (size_t)MM * 64, (size_t)1536 * 64, (size_t)MM * DIN,
        dtws, nullptr, b_dt, nullptr);

  // out = base; selective scan; out += sum_e y_e @ (w_e*W_out_e) via atomics
  copy4_k<<<MM * DD / 4 / 256, 256, 0, stream>>>(base, out, MM * DD / 4);
  scan_k<<<EXP * BB * DIN * 16 / 256, 256, 0, stream>>>(dtws, xsws, gws, dblf, A_log, D_skip);
  mfma_gemm_k<3><<<dim3(6, 32, EXP), 256, 0, stream>>>(xsws, WoutT, 1536, DIN,
        (size_t)MM * DIN, (size_t)768 * 1536, 0,
        nullptr, nullptr, nullptr, out);
}

// Round 13
// 879.056 us; speedup vs baseline: 1.5087x; 1.0219x over previous
//
#include <hip/hip_runtime.h>
#include <hip/hip_bf16.h>

typedef __hip_bfloat16 bf16;
typedef unsigned short u16;
typedef __attribute__((ext_vector_type(8))) short s16x8;
typedef __attribute__((ext_vector_type(4))) short s16x4;
typedef __attribute__((ext_vector_type(4))) float f32x4;

#define EXP 3
#define BB  4
#define LL  1024
#define DD  768
#define DSN 64
#define DIN 1536
#define DTR 48
#define MM  4096       // B*L rows per expert

struct alignas(8)  bf16x4 { bf16 v[4]; };
struct alignas(16) bf16x8 { bf16 v[8]; };

__device__ __forceinline__ float siluf(float x) { return x / (1.f + __expf(-x)); }
__device__ __forceinline__ float softplusf(float x) { return (x > 15.f) ? x : log1pf(__expf(x)); }
__device__ __forceinline__ float bf2f(u16 h) { union { unsigned u; float f; } x; x.u = ((unsigned)h) << 16; return x.f; }

// elementwise bf16 product of two packed 8-vectors (f32 math, RNE back)
__device__ __forceinline__ s16x8 gmul8(s16x8 a, s16x8 g) {
  s16x8 r;
#pragma unroll
  for (int j = 0; j < 8; j++) {
    union { bf16 b; u16 u; } cv;
    cv.b = (bf16)(bf2f((u16)a[j]) * bf2f((u16)g[j]));
    r[j] = (short)cv.u;
  }
  return r;
}

// DPP row-rotate add; rotate-allreduce {8,4,2,1} -> full 16-lane sum in every lane.
template <int CTRL>
__device__ __forceinline__ float ror_add(float x) {
  int y = __builtin_amdgcn_update_dpp(0, __float_as_int(x), CTRL, 0xf, 0xf, true);
  return x + __int_as_float(y);
}

// ---------------- LayerNorm apply + bf16 convert: per_ch -> Abf ----------------
__launch_bounds__(256)
__global__ void ln_apply_k(const float* __restrict__ pc, const float* __restrict__ lng,
                           const float* __restrict__ lnb, bf16* __restrict__ out) {
  int row  = blockIdx.x * 4 + (threadIdx.x >> 6);
  int lane = threadIdx.x & 63;
  const float* x = pc + (size_t)row * DD;
  float4 v[3];
  float s = 0.f, sq = 0.f;
#pragma unroll
  for (int i = 0; i < 3; i++) {
    v[i] = *(const float4*)(x + lane * 4 + i * 256);
    s  += v[i].x + v[i].y + v[i].z + v[i].w;
    sq += v[i].x * v[i].x + v[i].y * v[i].y + v[i].z * v[i].z + v[i].w * v[i].w;
  }
#pragma unroll
  for (int o = 1; o < 64; o <<= 1) { s += __shfl_xor(s, o); sq += __shfl_xor(sq, o); }
  float mu = s * (1.f / 768.f);
  float rs = rsqrtf(sq * (1.f / 768.f) - mu * mu + 1e-5f);
  bf16* op = out + (size_t)row * DD;
#pragma unroll
  for (int i = 0; i < 3; i++) {
    int col = lane * 4 + i * 256;
    float4 g4 = *(const float4*)(lng + col);
    float4 b4 = *(const float4*)(lnb + col);
    bf16x4 pk;
    pk.v[0] = (bf16)((v[i].x - mu) * rs * g4.x + b4.x);
    pk.v[1] = (bf16)((v[i].y - mu) * rs * g4.y + b4.y);
    pk.v[2] = (bf16)((v[i].z - mu) * rs * g4.z + b4.z);
    pk.v[3] = (bf16)((v[i].w - mu) * rs * g4.w + b4.w);
    *(bf16x4*)(op + col) = pk;
  }
}

// ---------------- transpose + f32->bf16 weight conversion ----------------
__launch_bounds__(256)
__global__ void tcvt_k(const float* __restrict__ in, bf16* __restrict__ out,
                       int Ksrc, int ldin, int ldout,
                       size_t sIn, size_t sOut, int mode, const float* __restrict__ alphap) {
  __shared__ float tl[32][33];
  int z = blockIdx.z;
  const float* src = in + (size_t)z * sIn;
  bf16* dst = out + (size_t)z * sOut;
  int n0 = blockIdx.x * 32, k0 = blockIdx.y * 32;
  int tx = threadIdx.x, ty = threadIdx.y;
  int n = n0 + tx;
  int c = n; bool nv = true;
  if (mode == 1) {
    if (n < 48)       c = n;
    else if (n < 64)  nv = false;
    else if (n < 192) c = n - 16;
    else              nv = false;
  }
  float scale = 1.f;
  if (mode == 2) {
    float a0 = alphap[0], a1 = alphap[1], a2 = alphap[2];
    float mx = fmaxf(a0, fmaxf(a1, a2));
    float e0 = __expf(a0 - mx), e1 = __expf(a1 - mx), e2 = __expf(a2 - mx);
    scale = ((z == 0) ? e0 : (z == 1) ? e1 : e2) / (e0 + e1 + e2);
  }
#pragma unroll
  for (int i = 0; i < 32; i += 8) {
    int k = k0 + ty + i;
    float v = (nv && k < Ksrc) ? src[(size_t)k * ldin + c] : 0.f;
    tl[ty + i][tx] = v * scale;
  }
  __syncthreads();
#pragma unroll
  for (int i = 0; i < 32; i += 8) {
    dst[(size_t)(n0 + ty + i) * ldout + (k0 + tx)] = (bf16)tl[tx][ty + i];
  }
}

// ---------------- causal depthwise conv (K=4) + SiLU, 8 channels/thread ----------------
__launch_bounds__(256)
__global__ void conv_silu_k(const bf16* __restrict__ xp, const float* __restrict__ cw,
                            const float* __restrict__ cb, bf16* __restrict__ xs) {
  long i = ((long)blockIdx.x * 256 + threadIdx.x) * 8;   // elem index, 8 channels
  int  c  = (int)(i % DIN);
  long rl = i / DIN;                                     // (e*B + b)*L + l
  int  l  = (int)(rl & (LL - 1));
  int  e  = (int)(rl >> 12);                             // B*L = 4096
  const float* wp  = cw + (size_t)e * DIN * 4 + (size_t)c * 4;
  const float* cbp = cb + (size_t)e * DIN + c;
  float acc[8];
#pragma unroll
  for (int j = 0; j < 8; j++) acc[j] = cbp[j];
#pragma unroll
  for (int tap = 0; tap < 4; tap++) {
    if (l - 3 + tap >= 0) {
      s16x8 xv = *(const s16x8*)(const void*)(xp + (rl + tap - 3) * DIN + c);
#pragma unroll
      for (int j = 0; j < 8; j++)
        acc[j] = fmaf(bf2f((u16)xv[j]), wp[j * 4 + tap], acc[j]);
    }
  }
  bf16x8 pk;
#pragma unroll
  for (int j = 0; j < 8; j++) pk.v[j] = (bf16)siluf(acc[j]);
  *(bf16x8*)(xs + rl * DIN + c) = pk;
}

// ---------------- bf16 MFMA GEMM, 128x128 tile, BK=64 (2x BK=32 panels) ----------------
// Two k-permuted BK=32 LDS panels per barrier pair (halves __syncthreads count
// vs R5's BK=32; layout/fragment reads unchanged, proven). 32 KB LDS total.
// MODE 0: xz GEMM  -> o0=xp bf16 (n<DIN), o1=silu(z) bf16
// MODE 1: dbl GEMM -> gc<64 -> dblp bf16 (ld 64); gc 64..191 -> dblf f32 [M][128]
// MODE 2: dt GEMM  -> o0=softplus(acc + bias[gc]) bf16 (row-major [M][DIN])
// MODE 3: out GEMM, A pre-multiplied by gate gat (y*g) during staging ->
//         atomicAdd into outp (W_out pre-scaled by softmax(alpha))
template<int MODE>
__launch_bounds__(256)
__global__ void mfma_gemm_k(const bf16* __restrict__ A, const bf16* __restrict__ Bt,
                            int Kdim, int lda,
                            size_t sA, size_t sB, size_t sO,
                            bf16* __restrict__ o0, bf16* __restrict__ o1,
                            const float* __restrict__ bias,
                            float* __restrict__ outp,
                            const bf16* __restrict__ gat) {
  __shared__ short As[128 * 64];   // 2 panels x 128 rows x 32 shorts
  __shared__ short Bs[128 * 64];
  int z = blockIdx.z;
  A  += (size_t)z * sA;
  Bt += (size_t)z * sB;
  if (o0) o0 += (size_t)z * sO;
  if (o1) o1 += (size_t)z * sO;
  if constexpr (MODE == 1) outp += (size_t)z * (size_t)MM * 128;
  if constexpr (MODE == 3) gat += (size_t)z * sA;
  const float* bz = (MODE == 2) ? bias + (size_t)z * DIN : bias;

  int t = threadIdx.x;
  int l = t & 63, w = t >> 6;
  int wr = w >> 1, wc = w & 1;
  int n0 = blockIdx.x * 128, r0 = blockIdx.y * 128;

  int row = t >> 2, c3 = t & 3, col = c3 * 8;
  int plo = ((c3 & 1) ? 16 : 0) + ((c3 & 2) ? 4 : 0);   // k-permuted LDS slot
  int lrow = (l & 15) * 32 + (l >> 4) * 8;

  f32x4 acc[4][4] = {};

#define PUT(DST, ROW, V)                                                        \
  { *(s16x4*)((DST) + (ROW) * 32 + plo)     = __builtin_shufflevector(V, V, 0, 1, 2, 3); \
    *(s16x4*)((DST) + (ROW) * 32 + plo + 8) = __builtin_shufflevector(V, V, 4, 5, 6, 7); }

  for (int k0 = 0; k0 < Kdim; k0 += 64) {
    const bf16* pa = A  + (size_t)(r0 + row) * lda  + k0 + col;
    const bf16* pb = Bt + (size_t)(n0 + row) * Kdim + k0 + col;
    s16x8 va0 = *(const s16x8*)(const void*)(pa);
    s16x8 va1 = *(const s16x8*)(const void*)(pa + (size_t)64 * lda);
    s16x8 va2 = *(const s16x8*)(const void*)(pa + 32);
    s16x8 va3 = *(const s16x8*)(const void*)(pa + (size_t)64 * lda + 32);
    s16x8 vb0 = *(const s16x8*)(const void*)(pb);
    s16x8 vb1 = *(const s16x8*)(const void*)(pb + (size_t)64 * Kdim);
    s16x8 vb2 = *(const s16x8*)(const void*)(pb + 32);
    s16x8 vb3 = *(const s16x8*)(const void*)(pb + (size_t)64 * Kdim + 32);
    if constexpr (MODE == 3) {   // gate y*g during staging
      const bf16* pg = gat + (size_t)(r0 + row) * lda + k0 + col;
      va0 = gmul8(va0, *(const s16x8*)(const void*)(pg));
      va1 = gmul8(va1, *(const s16x8*)(const void*)(pg + (size_t)64 * lda));
      va2 = gmul8(va2, *(const s16x8*)(const void*)(pg + 32));
      va3 = gmul8(va3, *(const s16x8*)(const void*)(pg + (size_t)64 * lda + 32));
    }
    __syncthreads();   // previous iteration's ds_reads done
    PUT(As, row, va0)  PUT(As, row + 64, va1)
    PUT(As + 4096, row, va2)  PUT(As + 4096, row + 64, va3)
    PUT(Bs, row, vb0)  PUT(Bs, row + 64, vb1)
    PUT(Bs + 4096, row, vb2)  PUT(Bs + 4096, row + 64, vb3)
    __syncthreads();
#pragma unroll
    for (int p = 0; p < 2; p++) {
      const short* as = As + p * 4096;
      const short* bs = Bs + p * 4096;
      s16x8 af[4], bfv[4];
#pragma unroll
      for (int m = 0; m < 4; m++) af[m]  = *(const s16x8*)(as + (wr * 64 + m * 16) * 32 + lrow);
#pragma unroll
      for (int n = 0; n < 4; n++) bfv[n] = *(const s16x8*)(bs + (wc * 64 + n * 16) * 32 + lrow);
#pragma unroll
      for (int m = 0; m < 4; m++)
#pragma unroll
        for (int n = 0; n < 4; n++)
          acc[m][n] = __builtin_amdgcn_mfma_f32_16x16x32_bf16(af[m], bfv[n], acc[m][n], 0, 0, 0);
    }
  }
#undef PUT

  int rb = r0 + wr * 64 + ((l >> 4) << 2);
  int cb = n0 + wc * 64 + (l & 15);
#pragma unroll
  for (int m = 0; m < 4; m++)
#pragma unroll
    for (int n = 0; n < 4; n++)
#pragma unroll
      for (int r = 0; r < 4; r++) {
        int gr = rb + m * 16 + r;
        int gc = cb + n * 16;
        float v = acc[m][n][r];
        if constexpr (MODE == 0) {
          if (n0 < DIN) o0[(size_t)gr * DIN + gc] = (bf16)v;
          else          o1[(size_t)gr * DIN + (gc - DIN)] = (bf16)siluf(v);
        } else if constexpr (MODE == 1) {
          if (gc < 64)       o0[(size_t)gr * 64 + gc] = (bf16)v;
          else if (gc < 192) outp[(size_t)gr * 128 + (gc - 64)] = v;
        } else if constexpr (MODE == 2) {
          o0[(size_t)gr * DIN + gc] = (bf16)softplusf(v + bz[gc]);
        } else {
          atomicAdd(&outp[(size_t)gr * DD + gc], v);
        }
      }
}

// ---------------- out = base (init before atomic accumulation) ----------------
__launch_bounds__(256)
__global__ void copy4_k(const float* __restrict__ s, float* __restrict__ d, int n4) {
  int i = blockIdx.x * 256 + threadIdx.x;
  if (i < n4) ((float4*)d)[i] = ((const float4*)s)[i];
}

// ---------------- selective scan: 16 lanes/channel, 4 states/lane ----------------
// Measured-best structure (R5/R8/R12: 488 us, 65% VALUBusy, VGPR 24), minus
// the gate stream: stores UNGATED y = u*dskip + p (gate applied in MODE3
// A-staging). One fewer VMEM stream + mul in the 1024-step serial loop.
__launch_bounds__(256)
__global__ void scan_k(const bf16* __restrict__ dtb, bf16* __restrict__ xsb,
                       const float* __restrict__ dbl,
                       const float* __restrict__ A_log, const float* __restrict__ Dsk) {
  int gt = blockIdx.x * 256 + threadIdx.x;
  int sg = gt & 15;             // states [sg*4, sg*4+4)
  int cidx = gt >> 4;           // (e*B + b)*DIN + d
  int d  = cidx % DIN;
  int eb = cidx / DIN;
  int e  = eb >> 2;             // B == 4

  float4 Ar = *(const float4*)(A_log + ((size_t)e * DIN + d) * DSN + sg * 4);
  const float LOG2E = 1.44269504088896f;
  float4 A2;
  A2.x = -__expf(Ar.x) * LOG2E;
  A2.y = -__expf(Ar.y) * LOG2E;
  A2.z = -__expf(Ar.z) * LOG2E;
  A2.w = -__expf(Ar.w) * LOG2E;
  float4 h = {0.f, 0.f, 0.f, 0.f};
  float dskip = Dsk[(size_t)e * DIN + d];

  unsigned idx  = (unsigned)eb * (LL * DIN) + (unsigned)d;   // bf16 elem offset
  unsigned bofs = (unsigned)eb * (LL * 128) + (unsigned)(sg * 4);

  // prefetch l = 0  (final iteration prefetches 1 row past this (e,b) slice;
  // lands in the next ws region, value unused -- safe)
  float dtv = (float)dtb[idx];
  float u   = (float)xsb[idx];
  float4 Bv = *(const float4*)(dbl + bofs);
  float4 Cv = *(const float4*)(dbl + bofs + 64);

#pragma unroll 4
  for (int l = 0; l < LL; ++l) {
    unsigned idxn = idx + DIN;
    unsigned bofn = bofs + 128;
    float dtn = (float)dtb[idxn];
    float un  = (float)xsb[idxn];
    float4 Bn = *(const float4*)(dbl + bofn);
    float4 Cn = *(const float4*)(dbl + bofn + 64);

    float du = dtv * u;
    float4 dA;
    dA.x = __builtin_amdgcn_exp2f(dtv * A2.x);
    dA.y = __builtin_amdgcn_exp2f(dtv * A2.y);
    dA.z = __builtin_amdgcn_exp2f(dtv * A2.z);
    dA.w = __builtin_amdgcn_exp2f(dtv * A2.w);
    h.x = fmaf(dA.x, h.x, du * Bv.x);
    h.y = fmaf(dA.y, h.y, du * Bv.y);
    h.z = fmaf(dA.z, h.z, du * Bv.z);
    h.w = fmaf(dA.w, h.w, du * Bv.w);
    float p = fmaf(h.x, Cv.x, fmaf(h.y, Cv.y, fmaf(h.z, Cv.z, h.w * Cv.w)));
    p = ror_add<0x128>(p);   // row_ror:8
    p = ror_add<0x124>(p);   // row_ror:4
    p = ror_add<0x122>(p);   // row_ror:2
    p = ror_add<0x121>(p);   // row_ror:1
    if (sg == 0) {
      xsb[idx] = (bf16)fmaf(u, dskip, p);   // UNGATED y over xs
    }
    idx = idxn; bofs = bofn;
    dtv = dtn; u = un; Bv = Bn; Cv = Cn;
  }
}

extern "C" void kernel_launch(void* const* d_in, const int* in_sizes, int n_in,
                              void* d_out, int out_size, void* d_ws, size_t ws_size,
                              hipStream_t stream) {
  const float* base   = (const float*)d_in[0];
  const float* per_ch = (const float*)d_in[1];
  const float* alpha  = (const float*)d_in[2];
  const float* ln_g   = (const float*)d_in[3];
  const float* ln_b   = (const float*)d_in[4];
  const float* W_in   = (const float*)d_in[5];
  const float* conv_w = (const float*)d_in[6];
  const float* conv_b = (const float*)d_in[7];
  const float* W_x    = (const float*)d_in[8];
  const float* W_dt   = (const float*)d_in[9];
  const float* b_dt   = (const float*)d_in[10];
  const float* A_log  = (const float*)d_in[11];
  const float* D_skip = (const float*)d_in[12];
  const float* W_out  = (const float*)d_in[13];
  float* out = (float*)d_out;
  (void)in_sizes; (void)n_in; (void)out_size; (void)ws_size;

  // Workspace layout (131.9 MB), lifetime overlays:
  //  R1 [37.75M]: Abf (18.87M) -> xs (row-major) -> UNGATED y (scan in-place)
  //  R2 [37.75M]: g = silu(z)  (consumed by MODE3 staging)
  //  R3 [37.75M]: xp -> dt (row-major [M][DIN])
  //  R4 [14.16M]: W_inT -> [WoutT 7.08M | dblf f32 row-major [E*M][128] 6.29M]
  //  R5 [ 2.36M]: W_xT ;  R6 [0.59M]: W_dtT ;  R7 [1.57M]: dblp bf16 (ld 64)
  char* ws = (char*)d_ws;
  const size_t R = (size_t)EXP * MM * DIN * 2;            // 37,748,736
  bf16* Abf   = (bf16*)ws;
  bf16* xsws  = (bf16*)ws;
  bf16* gws   = (bf16*)(ws + R);
  bf16* dtws  = (bf16*)(ws + 2 * R);
  char* R4    = ws + 3 * R;
  bf16*  WinT  = (bf16*)R4;
  bf16*  WoutT = (bf16*)R4;                               // overlays WinT after MODE0
  float* dblf  = (float*)(R4 + 7077888);                  // E*M*128 f32 = 6.29M
  bf16* WxT   = (bf16*)(ws + 3 * R + 14155776);
  bf16* WdtT  = (bf16*)(ws + 3 * R + 14155776 + 2359296);
  bf16* dblp  = (bf16*)(ws + 3 * R + 14155776 + 2359296 + 589824);

  dim3 blk2(32, 8);

  // prep: LN->bf16, weight transposes (bf16, B^T layout)
  ln_apply_k<<<EXP * BB * LL / 4, 256, 0, stream>>>(per_ch, ln_g, ln_b, Abf);
  tcvt_k<<<dim3(96, 24, EXP), blk2, 0, stream>>>(W_in, WinT, 768, 3072, 768,
        (size_t)768 * 3072, (size_t)3072 * 768, 0, nullptr);
  tcvt_k<<<dim3(8, 48, EXP), blk2, 0, stream>>>(W_x, WxT, 1536, 176, 1536,
        (size_t)1536 * 176, (size_t)256 * 1536, 1, nullptr);
  tcvt_k<<<dim3(48, 2, EXP), blk2, 0, stream>>>(W_dt, WdtT, 48, 1536, 64,
        (size_t)48 * 1536, (size_t)1536 * 64, 0, nullptr);

  // xz = Abf @ W_in -> xp (dtws), silu(z) (gws)
  mfma_gemm_k<0><<<dim3(24, 32, EXP), 256, 0, stream>>>(Abf, WinT, 768, DD,
        (size_t)MM * DD, (size_t)3072 * 768, (size_t)MM * DIN,
        dtws, gws, nullptr, nullptr, nullptr);

  // W_outT (pre-scaled by softmax(alpha)) -- overlays W_inT, safe after MODE0
  tcvt_k<<<dim3(24, 48, EXP), blk2, 0, stream>>>(W_out, WoutT, 1536, 768, 1536,
        (size_t)1536 * 768, (size_t)768 * 1536, 2, alpha);

  // causal conv + silu -> xs (overlays Abf, safe after MODE0)
  conv_silu_k<<<EXP * BB * LL * DIN / 8 / 256, 256, 0, stream>>>(dtws, conv_w, conv_b, xsws);

  // dbl = xs @ W_x: dt cols -> dblp (bf16, ld 64); B|C -> dblf f32 row-major [M][128]
  mfma_gemm_k<1><<<dim3(2, 32, EXP), 256, 0, stream>>>(xsws, WxT, 1536, DIN,
        (size_t)MM * DIN, (size_t)256 * 1536, (size_t)MM * 64,
        dblp, nullptr, nullptr, dblf, nullptr);

  // dt = softplus(dblp @ W_dt + b_dt) -> dtws
  mfma_gemm_k<2><<<dim3(12, 32, EXP), 256, 0, stream>>>(dblp, WdtT, 64, 64,
        (size_t)MM * 64, (size_t)1536 * 64, (size_t)MM * DIN,
        dtws, nullptr, b_dt, nullptr, nullptr);

  // out = base; scan (ungated y); out += sum_e (y*g)_e @ (w_e*W_out_e)
  copy4_k<<<MM * DD / 4 / 256, 256, 0, stream>>>(base, out, MM * DD / 4);
  scan_k<<<EXP * BB * DIN * 16 / 256, 256, 0, stream>>>(dtws, xsws, dblf, A_log, D_skip);
  mfma_gemm_k<3><<<dim3(6, 32, EXP), 256, 0, stream>>>(xsws, WoutT, 1536, DIN,
        (size_t)MM * DIN, (size_t)768 * 1536, 0,
        nullptr, nullptr, nullptr, out, gws);
}

// Round 14
// 840.620 us; speedup vs baseline: 1.5777x; 1.0457x over previous
//
#include <hip/hip_runtime.h>
#include <hip/hip_bf16.h>

typedef __hip_bfloat16 bf16;
typedef unsigned short u16;
typedef __attribute__((ext_vector_type(8))) short s16x8;
typedef __attribute__((ext_vector_type(4))) short s16x4;
typedef __attribute__((ext_vector_type(4))) float f32x4;

#define EXP 3
#define BB  4
#define LL  1024
#define DD  768
#define DSN 64
#define DIN 1536
#define DTR 48
#define MM  4096       // B*L rows per expert

struct alignas(8)  bf16x4 { bf16 v[4]; };
struct alignas(16) bf16x8 { bf16 v[8]; };

__device__ __forceinline__ float siluf(float x) { return x / (1.f + __expf(-x)); }
__device__ __forceinline__ float bf2f(u16 h) { union { unsigned u; float f; } x; x.u = ((unsigned)h) << 16; return x.f; }

// fast softplus: ln(1+e^x) = max(x,0) + ln2*log2(1+exp2(-|x|*log2e)); raw
// v_exp_f32/v_log_f32, no libm. bf16 output -> precision ample.
__device__ __forceinline__ float softplusf(float x) {
  const float LOG2E = 1.44269504088896f, LN2 = 0.69314718055995f;
  float t = __builtin_amdgcn_exp2f(-fabsf(x) * LOG2E);
  return fmaxf(x, 0.f) + LN2 * __builtin_amdgcn_logf(1.f + t);
}

// elementwise bf16 product of two packed 8-vectors (f32 math, RNE back)
__device__ __forceinline__ s16x8 gmul8(s16x8 a, s16x8 g) {
  s16x8 r;
#pragma unroll
  for (int j = 0; j < 8; j++) {
    union { bf16 b; u16 u; } cv;
    cv.b = (bf16)(bf2f((u16)a[j]) * bf2f((u16)g[j]));
    r[j] = (short)cv.u;
  }
  return r;
}

// DPP row-rotate add; rotate-allreduce {8,4,2,1} -> full 16-lane sum in every lane.
template <int CTRL>
__device__ __forceinline__ float ror_add(float x) {
  int y = __builtin_amdgcn_update_dpp(0, __float_as_int(x), CTRL, 0xf, 0xf, true);
  return x + __int_as_float(y);
}

// ---------------- LayerNorm apply + bf16 convert: per_ch -> Abf ----------------
__launch_bounds__(256)
__global__ void ln_apply_k(const float* __restrict__ pc, const float* __restrict__ lng,
                           const float* __restrict__ lnb, bf16* __restrict__ out) {
  int row  = blockIdx.x * 4 + (threadIdx.x >> 6);
  int lane = threadIdx.x & 63;
  const float* x = pc + (size_t)row * DD;
  float4 v[3];
  float s = 0.f, sq = 0.f;
#pragma unroll
  for (int i = 0; i < 3; i++) {
    v[i] = *(const float4*)(x + lane * 4 + i * 256);
    s  += v[i].x + v[i].y + v[i].z + v[i].w;
    sq += v[i].x * v[i].x + v[i].y * v[i].y + v[i].z * v[i].z + v[i].w * v[i].w;
  }
#pragma unroll
  for (int o = 1; o < 64; o <<= 1) { s += __shfl_xor(s, o); sq += __shfl_xor(sq, o); }
  float mu = s * (1.f / 768.f);
  float rs = rsqrtf(sq * (1.f / 768.f) - mu * mu + 1e-5f);
  bf16* op = out + (size_t)row * DD;
#pragma unroll
  for (int i = 0; i < 3; i++) {
    int col = lane * 4 + i * 256;
    float4 g4 = *(const float4*)(lng + col);
    float4 b4 = *(const float4*)(lnb + col);
    bf16x4 pk;
    pk.v[0] = (bf16)((v[i].x - mu) * rs * g4.x + b4.x);
    pk.v[1] = (bf16)((v[i].y - mu) * rs * g4.y + b4.y);
    pk.v[2] = (bf16)((v[i].z - mu) * rs * g4.z + b4.z);
    pk.v[3] = (bf16)((v[i].w - mu) * rs * g4.w + b4.w);
    *(bf16x4*)(op + col) = pk;
  }
}

// ---------------- transpose + f32->bf16 weight conversion ----------------
__launch_bounds__(256)
__global__ void tcvt_k(const float* __restrict__ in, bf16* __restrict__ out,
                       int Ksrc, int ldin, int ldout,
                       size_t sIn, size_t sOut, int mode, const float* __restrict__ alphap) {
  __shared__ float tl[32][33];
  int z = blockIdx.z;
  const float* src = in + (size_t)z * sIn;
  bf16* dst = out + (size_t)z * sOut;
  int n0 = blockIdx.x * 32, k0 = blockIdx.y * 32;
  int tx = threadIdx.x, ty = threadIdx.y;
  int n = n0 + tx;
  int c = n; bool nv = true;
  if (mode == 1) {
    if (n < 48)       c = n;
    else if (n < 64)  nv = false;
    else if (n < 192) c = n - 16;
    else              nv = false;
  }
  float scale = 1.f;
  if (mode == 2) {
    float a0 = alphap[0], a1 = alphap[1], a2 = alphap[2];
    float mx = fmaxf(a0, fmaxf(a1, a2));
    float e0 = __expf(a0 - mx), e1 = __expf(a1 - mx), e2 = __expf(a2 - mx);
    scale = ((z == 0) ? e0 : (z == 1) ? e1 : e2) / (e0 + e1 + e2);
  }
#pragma unroll
  for (int i = 0; i < 32; i += 8) {
    int k = k0 + ty + i;
    float v = (nv && k < Ksrc) ? src[(size_t)k * ldin + c] : 0.f;
    tl[ty + i][tx] = v * scale;
  }
  __syncthreads();
#pragma unroll
  for (int i = 0; i < 32; i += 8) {
    dst[(size_t)(n0 + ty + i) * ldout + (k0 + tx)] = (bf16)tl[tx][ty + i];
  }
}

// ---------------- causal depthwise conv (K=4) + SiLU, 8 channels/thread ----------------
__launch_bounds__(256)
__global__ void conv_silu_k(const bf16* __restrict__ xp, const float* __restrict__ cw,
                            const float* __restrict__ cb, bf16* __restrict__ xs) {
  long i = ((long)blockIdx.x * 256 + threadIdx.x) * 8;   // elem index, 8 channels
  int  c  = (int)(i % DIN);
  long rl = i / DIN;                                     // (e*B + b)*L + l
  int  l  = (int)(rl & (LL - 1));
  int  e  = (int)(rl >> 12);                             // B*L = 4096
  const float* wp  = cw + (size_t)e * DIN * 4 + (size_t)c * 4;
  const float* cbp = cb + (size_t)e * DIN + c;
  float acc[8];
#pragma unroll
  for (int j = 0; j < 8; j++) acc[j] = cbp[j];
#pragma unroll
  for (int tap = 0; tap < 4; tap++) {
    if (l - 3 + tap >= 0) {
      s16x8 xv = *(const s16x8*)(const void*)(xp + (rl + tap - 3) * DIN + c);
#pragma unroll
      for (int j = 0; j < 8; j++)
        acc[j] = fmaf(bf2f((u16)xv[j]), wp[j * 4 + tap], acc[j]);
    }
  }
  bf16x8 pk;
#pragma unroll
  for (int j = 0; j < 8; j++) pk.v[j] = (bf16)siluf(acc[j]);
  *(bf16x8*)(xs + rl * DIN + c) = pk;
}

// ---------------- bf16 MFMA GEMM, 128x128 tile, BK=32 (R5 measured-best body) ----------------
// MODE 0: xz GEMM  -> o0=xp bf16 (n<DIN), o1=silu(z) bf16
// MODE 1: dbl GEMM -> gc<64 -> dblp bf16 (ld 64); gc 64..191 -> dblf f32 [M][128]
// MODE 2: dt GEMM  -> o0=softplus(acc + bias[gc]) bf16 (row-major [M][DIN])
// MODE 3: out GEMM, A pre-multiplied by gate gat (y*g) at load ->
//         atomicAdd into outp (W_out pre-scaled by softmax(alpha))
template<int MODE>
__launch_bounds__(256)
__global__ void mfma_gemm_k(const bf16* __restrict__ A, const bf16* __restrict__ Bt,
                            int Kdim, int lda,
                            size_t sA, size_t sB, size_t sO,
                            bf16* __restrict__ o0, bf16* __restrict__ o1,
                            const float* __restrict__ bias,
                            float* __restrict__ outp,
                            const bf16* __restrict__ gat) {
  __shared__ short As[128 * 32];
  __shared__ short Bs[128 * 32];
  int z = blockIdx.z;
  A  += (size_t)z * sA;
  Bt += (size_t)z * sB;
  if (o0) o0 += (size_t)z * sO;
  if (o1) o1 += (size_t)z * sO;
  if constexpr (MODE == 1) outp += (size_t)z * (size_t)MM * 128;
  if constexpr (MODE == 3) gat += (size_t)z * sA;
  const float* bz = (MODE == 2) ? bias + (size_t)z * DIN : bias;

  int t = threadIdx.x;
  int l = t & 63, w = t >> 6;
  int wr = w >> 1, wc = w & 1;
  int n0 = blockIdx.x * 128, r0 = blockIdx.y * 128;

  int row = t >> 2, c3 = t & 3, col = c3 * 8;
  int plo = ((c3 & 1) ? 16 : 0) + ((c3 & 2) ? 4 : 0);   // k-permuted LDS slot
  int lrow = (l & 15) * 32 + (l >> 4) * 8;

  f32x4 acc[4][4] = {};

  for (int k0 = 0; k0 < Kdim; k0 += 32) {
    s16x8 va0 = *(const s16x8*)(const void*)(A  + (size_t)(r0 + row)      * lda  + k0 + col);
    s16x8 va1 = *(const s16x8*)(const void*)(A  + (size_t)(r0 + row + 64) * lda  + k0 + col);
    s16x8 vb0 = *(const s16x8*)(const void*)(Bt + (size_t)(n0 + row)      * Kdim + k0 + col);
    s16x8 vb1 = *(const s16x8*)(const void*)(Bt + (size_t)(n0 + row + 64) * Kdim + k0 + col);
    if constexpr (MODE == 3) {   // gate y*g at load
      const bf16* pg = gat + (size_t)(r0 + row) * lda + k0 + col;
      va0 = gmul8(va0, *(const s16x8*)(const void*)(pg));
      va1 = gmul8(va1, *(const s16x8*)(const void*)(pg + (size_t)64 * lda));
    }
    __syncthreads();   // previous iteration's ds_reads done
    *(s16x4*)(As + row * 32 + plo)          = __builtin_shufflevector(va0, va0, 0, 1, 2, 3);
    *(s16x4*)(As + row * 32 + plo + 8)      = __builtin_shufflevector(va0, va0, 4, 5, 6, 7);
    *(s16x4*)(As + (row + 64) * 32 + plo)     = __builtin_shufflevector(va1, va1, 0, 1, 2, 3);
    *(s16x4*)(As + (row + 64) * 32 + plo + 8) = __builtin_shufflevector(va1, va1, 4, 5, 6, 7);
    *(s16x4*)(Bs + row * 32 + plo)          = __builtin_shufflevector(vb0, vb0, 0, 1, 2, 3);
    *(s16x4*)(Bs + row * 32 + plo + 8)      = __builtin_shufflevector(vb0, vb0, 4, 5, 6, 7);
    *(s16x4*)(Bs + (row + 64) * 32 + plo)     = __builtin_shufflevector(vb1, vb1, 0, 1, 2, 3);
    *(s16x4*)(Bs + (row + 64) * 32 + plo + 8) = __builtin_shufflevector(vb1, vb1, 4, 5, 6, 7);
    __syncthreads();
    s16x8 af[4], bfv[4];
#pragma unroll
    for (int m = 0; m < 4; m++) af[m]  = *(const s16x8*)(As + (wr * 64 + m * 16) * 32 + lrow);
#pragma unroll
    for (int n = 0; n < 4; n++) bfv[n] = *(const s16x8*)(Bs + (wc * 64 + n * 16) * 32 + lrow);
#pragma unroll
    for (int m = 0; m < 4; m++)
#pragma unroll
      for (int n = 0; n < 4; n++)
        acc[m][n] = __builtin_amdgcn_mfma_f32_16x16x32_bf16(af[m], bfv[n], acc[m][n], 0, 0, 0);
  }

  int rb = r0 + wr * 64 + ((l >> 4) << 2);
  int cb = n0 + wc * 64 + (l & 15);
#pragma unroll
  for (int m = 0; m < 4; m++)
#pragma unroll
    for (int n = 0; n < 4; n++)
#pragma unroll
      for (int r = 0; r < 4; r++) {
        int gr = rb + m * 16 + r;
        int gc = cb + n * 16;
        float v = acc[m][n][r];
        if constexpr (MODE == 0) {
          if (n0 < DIN) o0[(size_t)gr * DIN + gc] = (bf16)v;
          else          o1[(size_t)gr * DIN + (gc - DIN)] = (bf16)siluf(v);
        } else if constexpr (MODE == 1) {
          if (gc < 64)       o0[(size_t)gr * 64 + gc] = (bf16)v;
          else if (gc < 192) outp[(size_t)gr * 128 + (gc - 64)] = v;
        } else if constexpr (MODE == 2) {
          o0[(size_t)gr * DIN + gc] = (bf16)softplusf(v + bz[gc]);
        } else {
          atomicAdd(&outp[(size_t)gr * DD + gc], v);
        }
      }
}

// ---------------- out = base (init before atomic accumulation) ----------------
__launch_bounds__(256)
__global__ void copy4_k(const float* __restrict__ s, float* __restrict__ d, int n4) {
  int i = blockIdx.x * 256 + threadIdx.x;
  if (i < n4) ((float4*)d)[i] = ((const float4*)s)[i];
}

// ---------------- selective scan: 16 lanes/channel, 4 states/lane ----------------
// Measured-best structure (448 us, 66% VALUBusy, VGPR 24): f32 B/C row-major,
// DPP rotate-allreduce, raw v_exp_f32, 32-bit offsets, depth-1 full prefetch
// + unroll 4; stores UNGATED y (gate applied in MODE3 A-staging).
__launch_bounds__(256)
__global__ void scan_k(const bf16* __restrict__ dtb, bf16* __restrict__ xsb,
                       const float* __restrict__ dbl,
                       const float* __restrict__ A_log, const float* __restrict__ Dsk) {
  int gt = blockIdx.x * 256 + threadIdx.x;
  int sg = gt & 15;             // states [sg*4, sg*4+4)
  int cidx = gt >> 4;           // (e*B + b)*DIN + d
  int d  = cidx % DIN;
  int eb = cidx / DIN;
  int e  = eb >> 2;             // B == 4

  float4 Ar = *(const float4*)(A_log + ((size_t)e * DIN + d) * DSN + sg * 4);
  const float LOG2E = 1.44269504088896f;
  float4 A2;
  A2.x = -__expf(Ar.x) * LOG2E;
  A2.y = -__expf(Ar.y) * LOG2E;
  A2.z = -__expf(Ar.z) * LOG2E;
  A2.w = -__expf(Ar.w) * LOG2E;
  float4 h = {0.f, 0.f, 0.f, 0.f};
  float dskip = Dsk[(size_t)e * DIN + d];

  unsigned idx  = (unsigned)eb * (LL * DIN) + (unsigned)d;   // bf16 elem offset
  unsigned bofs = (unsigned)eb * (LL * 128) + (unsigned)(sg * 4);

  // prefetch l = 0  (final iteration prefetches 1 row past this (e,b) slice;
  // lands in the next ws region, value unused -- safe)
  float dtv = (float)dtb[idx];
  float u   = (float)xsb[idx];
  float4 Bv = *(const float4*)(dbl + bofs);
  float4 Cv = *(const float4*)(dbl + bofs + 64);

#pragma unroll 4
  for (int l = 0; l < LL; ++l) {
    unsigned idxn = idx + DIN;
    unsigned bofn = bofs + 128;
    float dtn = (float)dtb[idxn];
    float un  = (float)xsb[idxn];
    float4 Bn = *(const float4*)(dbl + bofn);
    float4 Cn = *(const float4*)(dbl + bofn + 64);

    float du = dtv * u;
    float4 dA;
    dA.x = __builtin_amdgcn_exp2f(dtv * A2.x);
    dA.y = __builtin_amdgcn_exp2f(dtv * A2.y);
    dA.z = __builtin_amdgcn_exp2f(dtv * A2.z);
    dA.w = __builtin_amdgcn_exp2f(dtv * A2.w);
    h.x = fmaf(dA.x, h.x, du * Bv.x);
    h.y = fmaf(dA.y, h.y, du * Bv.y);
    h.z = fmaf(dA.z, h.z, du * Bv.z);
    h.w = fmaf(dA.w, h.w, du * Bv.w);
    float p = fmaf(h.x, Cv.x, fmaf(h.y, Cv.y, fmaf(h.z, Cv.z, h.w * Cv.w)));
    p = ror_add<0x128>(p);   // row_ror:8
    p = ror_add<0x124>(p);   // row_ror:4
    p = ror_add<0x122>(p);   // row_ror:2
    p = ror_add<0x121>(p);   // row_ror:1
    if (sg == 0) {
      xsb[idx] = (bf16)fmaf(u, dskip, p);   // UNGATED y over xs
    }
    idx = idxn; bofs = bofn;
    dtv = dtn; u = un; Bv = Bn; Cv = Cn;
  }
}

extern "C" void kernel_launch(void* const* d_in, const int* in_sizes, int n_in,
                              void* d_out, int out_size, void* d_ws, size_t ws_size,
                              hipStream_t stream) {
  const float* base   = (const float*)d_in[0];
  const float* per_ch = (const float*)d_in[1];
  const float* alpha  = (const float*)d_in[2];
  const float* ln_g   = (const float*)d_in[3];
  const float* ln_b   = (const float*)d_in[4];
  const float* W_in   = (const float*)d_in[5];
  const float* conv_w = (const float*)d_in[6];
  const float* conv_b = (const float*)d_in[7];
  const float* W_x    = (const float*)d_in[8];
  const float* W_dt   = (const float*)d_in[9];
  const float* b_dt   = (const float*)d_in[10];
  const float* A_log  = (const float*)d_in[11];
  const float* D_skip = (const float*)d_in[12];
  const float* W_out  = (const float*)d_in[13];
  float* out = (float*)d_out;
  (void)in_sizes; (void)n_in; (void)out_size; (void)ws_size;

  // Workspace layout (131.9 MB), lifetime overlays:
  //  R1 [37.75M]: Abf (18.87M) -> xs (row-major) -> UNGATED y (scan in-place)
  //  R2 [37.75M]: g = silu(z)  (consumed by MODE3 staging)
  //  R3 [37.75M]: xp -> dt (row-major [M][DIN])
  //  R4 [14.16M]: W_inT -> [WoutT 7.08M | dblf f32 row-major [E*M][128] 6.29M]
  //  R5 [ 2.36M]: W_xT ;  R6 [0.59M]: W_dtT ;  R7 [1.57M]: dblp bf16 (ld 64)
  char* ws = (char*)d_ws;
  const size_t R = (size_t)EXP * MM * DIN * 2;            // 37,748,736
  bf16* Abf   = (bf16*)ws;
  bf16* xsws  = (bf16*)ws;
  bf16* gws   = (bf16*)(ws + R);
  bf16* dtws  = (bf16*)(ws + 2 * R);
  char* R4    = ws + 3 * R;
  bf16*  WinT  = (bf16*)R4;
  bf16*  WoutT = (bf16*)R4;                               // overlays WinT after MODE0
  float* dblf  = (float*)(R4 + 7077888);                  // E*M*128 f32 = 6.29M
  bf16* WxT   = (bf16*)(ws + 3 * R + 14155776);
  bf16* WdtT  = (bf16*)(ws + 3 * R + 14155776 + 2359296);
  bf16* dblp  = (bf16*)(ws + 3 * R + 14155776 + 2359296 + 589824);

  dim3 blk2(32, 8);

  // prep: LN->bf16, weight transposes (bf16, B^T layout)
  ln_apply_k<<<EXP * BB * LL / 4, 256, 0, stream>>>(per_ch, ln_g, ln_b, Abf);
  tcvt_k<<<dim3(96, 24, EXP), blk2, 0, stream>>>(W_in, WinT, 768, 3072, 768,
        (size_t)768 * 3072, (size_t)3072 * 768, 0, nullptr);
  tcvt_k<<<dim3(8, 48, EXP), blk2, 0, stream>>>(W_x, WxT, 1536, 176, 1536,
        (size_t)1536 * 176, (size_t)256 * 1536, 1, nullptr);
  tcvt_k<<<dim3(48, 2, EXP), blk2, 0, stream>>>(W_dt, WdtT, 48, 1536, 64,
        (size_t)48 * 1536, (size_t)1536 * 64, 0, nullptr);

  // xz = Abf @ W_in -> xp (dtws), silu(z) (gws)
  mfma_gemm_k<0><<<dim3(24, 32, EXP), 256, 0, stream>>>(Abf, WinT, 768, DD,
        (size_t)MM * DD, (size_t)3072 * 768, (size_t)MM * DIN,
        dtws, gws, nullptr, nullptr, nullptr);

  // W_outT (pre-scaled by softmax(alpha)) -- overlays W_inT, safe after MODE0
  tcvt_k<<<dim3(24, 48, EXP), blk2, 0, stream>>>(W_out, WoutT, 1536, 768, 1536,
        (size_t)1536 * 768, (size_t)768 * 1536, 2, alpha);

  // causal conv + silu -> xs (overlays Abf, safe after MODE0)
  conv_silu_k<<<EXP * BB * LL * DIN / 8 / 256, 256, 0, stream>>>(dtws, conv_w, conv_b, xsws);

  // dbl = xs @ W_x: dt cols -> dblp (bf16, ld 64); B|C -> dblf f32 row-major [M][128]
  mfma_gemm_k<1><<<dim3(2, 32, EXP), 256, 0, stream>>>(xsws, WxT, 1536, DIN,
        (size_t)MM * DIN, (size_t)256 * 1536, (size_t)MM * 64,
        dblp, nullptr, nullptr, dblf, nullptr);

  // dt = softplus(dblp @ W_dt + b_dt) -> dtws
  mfma_gemm_k<2><<<dim3(12, 32, EXP), 256, 0, stream>>>(dblp, WdtT, 64, 64,
        (size_t)MM * 64, (size_t)1536 * 64, (size_t)MM * DIN,
        dtws, nullptr, b_dt, nullptr, nullptr);

  // out = base; scan (ungated y); out += sum_e (y*g)_e @ (w_e*W_out_e)
  copy4_k<<<MM * DD / 4 / 256, 256, 0, stream>>>(base, out, MM * DD / 4);
  scan_k<<<EXP * BB * DIN * 16 / 256, 256, 0, stream>>>(dtws, xsws, dblf, A_log, D_skip);
  mfma_gemm_k<3><<<dim3(6, 32, EXP), 256, 0, stream>>>(xsws, WoutT, 1536, DIN,
        (size_t)MM * DIN, (size_t)768 * 1536, 0,
        nullptr, nullptr, nullptr, out, gws);
}